// Round 9
// baseline (1586.616 us; speedup 1.0000x reference)
//
#include <hip/hip_runtime.h>
#include <math.h>

#define N_IMG 32
#define P2304 2304
#define CIN 512
#define CMID 256
#define C2 128
#define LEV 128

typedef _Float16 half8 __attribute__((ext_vector_type(8)));
typedef float f32x16 __attribute__((ext_vector_type(16)));
typedef unsigned short u16;
typedef unsigned int u32;

// ---------------- wave/block reduction helpers (wave = 64) ----------------
__device__ __forceinline__ float wredSum(float v){
#pragma unroll
  for (int o = 32; o > 0; o >>= 1) v += __shfl_down(v, o, 64);
  return v;
}
__device__ __forceinline__ float wredMax(float v){
#pragma unroll
  for (int o = 32; o > 0; o >>= 1) v = fmaxf(v, __shfl_down(v, o, 64));
  return v;
}
__device__ __forceinline__ float wredMin(float v){
#pragma unroll
  for (int o = 32; o > 0; o >>= 1) v = fminf(v, __shfl_down(v, o, 64));
  return v;
}

// async 16B global -> LDS (wave-uniform LDS base + lane*16)
__device__ __forceinline__ void gll16(const void* g, void* l){
  __builtin_amdgcn_global_load_lds(
      (const __attribute__((address_space(1))) void*)g,
      (__attribute__((address_space(3))) void*)l, 16, 0, 0);
}

// ---------------- weight prepack: split f32 -> (hi, lo*2^11) f16 frags ----
// Fragment order: frag index fi = ((kt*COTN + cot)*4 + c32)*64 + lam,
// holding 8 f16: element j is W[co = cot*128 + c32*32 + (lam&31)]
//                             [k  = kt*16 + (lam>>5)*8 + j]
__global__ void prep_w1_kernel(const float* __restrict__ w1,
                               uint4* __restrict__ Wh, uint4* __restrict__ Wl){
  int fid = blockIdx.x * 256 + threadIdx.x;     // 147456 frags
  int lam = fid & 63;
  int c32 = (fid >> 6) & 3;
  int cot = (fid >> 8) & 1;
  int kt  = fid >> 9;                           // 0..287
  int co = cot * 128 + c32 * 32 + (lam & 31);
  half8 vh, vl;
#pragma unroll
  for (int j = 0; j < 8; ++j){
    int k = kt * 16 + ((lam >> 5) << 3) + j;    // 0..4607
    int r = k >> 9;                             // tap
    int ci = k & 511;
    float v = w1[co * (CIN * 9) + ci * 9 + r];
    _Float16 h = (_Float16)v;
    vh[j] = h;
    vl[j] = (_Float16)((v - (float)h) * 2048.0f);
  }
  Wh[fid] = *(uint4*)&vh;
  Wl[fid] = *(uint4*)&vl;
}

__global__ void prep_w2_kernel(const float* __restrict__ w2,
                               uint4* __restrict__ Wh, uint4* __restrict__ Wl){
  int fid = blockIdx.x * 256 + threadIdx.x;     // 4096 frags
  int lam = fid & 63;
  int c32 = (fid >> 6) & 3;
  int kt  = fid >> 8;                           // 0..15
  int co = c32 * 32 + (lam & 31);
  half8 vh, vl;
#pragma unroll
  for (int j = 0; j < 8; ++j){
    int k = kt * 16 + ((lam >> 5) << 3) + j;    // 0..255
    float v = w2[co * CMID + k];
    _Float16 h = (_Float16)v;
    vh[j] = h;
    vl[j] = (_Float16)((v - (float)h) * 2048.0f);
  }
  Wh[fid] = *(uint4*)&vh;
  Wl[fid] = *(uint4*)&vl;
}

// s1 = g/sqrt(v+eps), t1 = b - m*s1  (bn folded to y*s1 + t1)
__global__ void prep_bn_kernel(const float* __restrict__ g1, const float* __restrict__ b1,
                               const float* __restrict__ m1, const float* __restrict__ v1,
                               float* __restrict__ s1, float* __restrict__ t1){
  int c = threadIdx.x;  // 256
  float s = g1[c] * (1.0f / sqrtf(v1[c] + 1e-5f));
  s1[c] = s;
  t1[c] = b1[c] - m1[c] * s;
}

// ---------------- FAST PATH: transpose+pad+split x (ck-chunked layout) ----
// x [n][512][48][48] f32 -> xh/xl [n_loc][ck=0..31][hp 50][wp 50][16ch] f16,
// zero halo. Position stride is 32B, so a wave reading 32 consecutive
// positions x 32B is one contiguous ~1KB run -> coalesced global_load_lds.
__global__ void prep_x_kernel(const float* __restrict__ x,
                              u16* __restrict__ xh, u16* __restrict__ xl,
                              int n0){
  __shared__ float tile[128 * 49];
  const int t = threadIdx.x;
  const int b = blockIdx.x;
  const int n_loc = b / 50;
  const int hp = b - n_loc * 50;
  const int n = n0 + n_loc;
  const int h = hp - 1;
  const bool vrow = (h >= 0) && (h < 48);
  const size_t base_n = (size_t)n_loc * 1280000;   // 32*2500*16 u16 per image
  for (int cc = 0; cc < 4; ++cc){                  // channels cc*128..+128
    if (vrow){
      const float* src = x + (((size_t)n * 512 + cc * 128) * 48 + h) * 48;
#pragma unroll
      for (int i = 0; i < 24; ++i){
        int idx = t + 256 * i;            // 6144 = 128c x 48w
        int w = idx % 48;
        int c = idx / 48;
        tile[c * 49 + w] = src[(size_t)c * 2304 + w];
      }
    }
    __syncthreads();
    // write 8 ck-chunks x 50 wp x 8 ch-pairs = 3200 u32 per array
    for (int i = 0; i < 13; ++i){
      int idx = t + 256 * i;
      if (idx < 3200){
        int ck_loc = idx / 400;           // 0..7
        int rem = idx - ck_loc * 400;
        int wp = rem >> 3;                // 0..49
        int clp = rem & 7;                // channel pair within 16
        int w = wp - 1;
        int c_loc = ck_loc * 16 + clp * 2;
        float v0 = 0.f, v1 = 0.f;
        if (vrow && (unsigned)w < 48u){
          v0 = tile[c_loc * 49 + w];
          v1 = tile[(c_loc + 1) * 49 + w];
        }
        _Float16 h0 = (_Float16)v0, h1 = (_Float16)v1;
        _Float16 l0 = (_Float16)((v0 - (float)h0) * 2048.0f);
        _Float16 l1 = (_Float16)((v1 - (float)h1) * 2048.0f);
        union { _Float16 hh[2]; u32 uu; } ph, pl;
        ph.hh[0] = h0; ph.hh[1] = h1;
        pl.hh[0] = l0; pl.hh[1] = l1;
        size_t off = base_n + ((size_t)(cc * 8 + ck_loc) * 2500
                               + hp * 50 + wp) * 16 + clp * 2;  // u16 idx
        *(u32*)(xh + off) = ph.uu;
        *(u32*)(xl + off) = pl.uu;
      }
    }
    __syncthreads();
  }
}

#define WAITV8  asm volatile("s_waitcnt vmcnt(8)"  ::: "memory")
#define WAITV6  asm volatile("s_waitcnt vmcnt(6)"  ::: "memory")
#define WAITV0  asm volatile("s_waitcnt vmcnt(0)"  ::: "memory")
#define BARSB { __builtin_amdgcn_s_barrier(); __builtin_amdgcn_sched_barrier(0); }

// ---------------- FAST conv1: 256p x 128co wide tile, BK=32 ---------------
// r8's proven 2-buffer/2-barrier/counted-vmcnt schedule at double p-width:
// halves the A (weight) staging per output -> total staged 5.3 -> 4.0 GB.
// 512 threads = 8 waves (2 cg x 4 pgw, each 64co x 64p). LDS 96 KiB
// (A 2x16 + B 2x32) -> 1 block/CU. 6 gll16/wave/stage (2 A-chunks + 4 B),
// steady vmcnt(6) = stage s+1 stays in flight across both barriers.
// launch_bounds(512,1): VGPR cap 512 -> NO spill (r7's fatal error was (512,4)).
template<int NC>
__global__ __launch_bounds__(512, 1) void conv1_wide_kernel(
    const u16* __restrict__ xh, const u16* __restrict__ xl,
    const uint4* __restrict__ Wh, const uint4* __restrict__ Wl,
    const float* __restrict__ s1, const float* __restrict__ t1,
    u16* __restrict__ yh, u16* __restrict__ yl, int n0)
{
  __shared__ _Float16 Abuf[2][2][2][2048];   // [buf][kf][hl][4 c32 x 512]
  __shared__ _Float16 Bbuf[2][2][2][4096];   // [buf][kf][hl][8 pgrp x 512]
  const int t = threadIdx.x;
  const int lam = t & 63;
  const int wid = t >> 6;                 // 0..7
  const int cg = wid & 1;                 // co-group of 64
  const int pgw = wid >> 1;               // p-group of 64 (compute role)

  const int xcd = blockIdx.x & 7;
  const int rest = blockIdx.x >> 3;       // [0, (NC/8)*18)
  const int n_loc = xcd * (NC / 8) + rest / 18;
  const int inner = rest % 18;
  const int pt = inner % 9;
  const int cot = inner / 9;
  const int n = n0 + n_loc;

  const int pbase = pt * 256;
  const int khi = lam >> 5;
  // staging position: wave wid stages B for p-group wid (32 positions)
  const int ps = pbase + wid * 32 + (lam & 31);
  const int phb = ps / 48, pwb = ps - (ps / 48) * 48;
  const u16* xh_n = xh + (size_t)n_loc * 1280000;
  const u16* xl_n = xl + (size_t)n_loc * 1280000;

  const int S = 144;                      // 9*512/32 BK=32 stages

  f32x16 acc_hh[2][2], acc_x[2][2];
#pragma unroll
  for (int a = 0; a < 2; ++a)
#pragma unroll
    for (int b = 0; b < 2; ++b){
#pragma unroll
      for (int e = 0; e < 16; ++e){ acc_hh[a][b][e] = 0.f; acc_x[a][b][e] = 0.f; }
    }

#define ISSUE_W(SV, BUF)                                                      \
  {                                                                           \
    int s_ = (SV);                                                            \
    int k0_ = 2 * s_;                                                         \
    _Pragma("unroll")                                                         \
    for (int i = 0; i < 2; ++i){                                              \
      int a_ = wid * 2 + i;               /* 0..15: hl|kf|c32 */              \
      int c32_ = a_ & 3;                                                      \
      int kf_ = (a_ >> 2) & 1;                                                \
      int hl_ = (a_ >> 3) & 1;                                                \
      int fg_ = ((k0_ + kf_) * 2 + cot) * 4 + c32_;                           \
      const uint4* sw_ = (hl_ ? Wl : Wh) + fg_ * 64 + lam;                    \
      gll16(sw_, &Abuf[BUF][kf_][hl_][c32_ * 512 + lam * 8]);                 \
    }                                                                         \
    int r_ = k0_ >> 5;                    /* tap 0..8 */                      \
    int ck0_ = k0_ & 31;                  /* 16-ch chunk base (even) */       \
    int qpp_ = (phb + r_ / 3) * 50 + (pwb + r_ % 3);                          \
    _Pragma("unroll")                                                         \
    for (int kf = 0; kf < 2; ++kf){                                           \
      size_t o_ = ((size_t)(ck0_ + kf) * 2500 + qpp_) * 16 + (khi << 3);      \
      gll16(xh_n + o_, &Bbuf[BUF][kf][0][wid * 512 + lam * 8]);               \
      gll16(xl_n + o_, &Bbuf[BUF][kf][1][wid * 512 + lam * 8]);               \
    }                                                                         \
  }

#define COMPUTE_W(CUR, KF)                                                    \
  {                                                                           \
    const int ct0 = cg * 2, pt0 = pgw * 2;                                    \
    half8 fAh[2], fAl[2], fBh[2], fBl[2];                                     \
    _Pragma("unroll")                                                         \
    for (int a = 0; a < 2; ++a){                                              \
      fAh[a] = *(half8*)&Abuf[CUR][KF][0][(ct0 + a) * 512 + lam * 8];         \
      fAl[a] = *(half8*)&Abuf[CUR][KF][1][(ct0 + a) * 512 + lam * 8];         \
      fBh[a] = *(half8*)&Bbuf[CUR][KF][0][(pt0 + a) * 512 + lam * 8];         \
      fBl[a] = *(half8*)&Bbuf[CUR][KF][1][(pt0 + a) * 512 + lam * 8];         \
    }                                                                         \
    _Pragma("unroll")                                                         \
    for (int a = 0; a < 2; ++a)                                               \
      _Pragma("unroll")                                                       \
      for (int b = 0; b < 2; ++b){                                            \
        acc_hh[a][b] = __builtin_amdgcn_mfma_f32_32x32x16_f16(                \
            fAh[a], fBh[b], acc_hh[a][b], 0, 0, 0);                           \
        acc_x[a][b] = __builtin_amdgcn_mfma_f32_32x32x16_f16(                 \
            fAh[a], fBl[b], acc_x[a][b], 0, 0, 0);                            \
        acc_x[a][b] = __builtin_amdgcn_mfma_f32_32x32x16_f16(                 \
            fAl[a], fBh[b], acc_x[a][b], 0, 0, 0);                            \
      }                                                                       \
  }

  ISSUE_W(0, 0);
  ISSUE_W(1, 1);

  for (int s = 0; s < S; ++s){
    if (s < S - 1) { WAITV6; } else { WAITV0; }
    BARSB;
    __builtin_amdgcn_s_setprio(1);
    COMPUTE_W(s & 1, 0);
    COMPUTE_W(s & 1, 1);
    __builtin_amdgcn_s_setprio(0);
    BARSB;
    if (s + 2 < S) ISSUE_W(s + 2, s & 1);
  }
#undef ISSUE_W
#undef COMPUTE_W

  // epilogue: combine hi/lo, bn+leaky, split f16, store y [n][co16][p][16]
  const int cobase = cot * 128 + cg * 64;
#pragma unroll
  for (int a = 0; a < 2; ++a){
#pragma unroll
    for (int b = 0; b < 2; ++b){
      const int pg = pbase + (pgw * 2 + b) * 32 + (lam & 31);
#pragma unroll
      for (int q = 0; q < 4; ++q){
        const int co0 = cobase + a * 32 + 8 * q + 4 * khi;
        const int co16 = co0 >> 4, col = co0 & 15;
        union { _Float16 h[4]; uint2 u; } Uh, Ul;
#pragma unroll
        for (int i = 0; i < 4; ++i){
          const int rg = 4 * q + i;
          const int co = co0 + i;
          float val = acc_hh[a][b][rg] + acc_x[a][b][rg] * (1.0f / 2048.0f);
          val = val * s1[co] + t1[co];
          val = val > 0.f ? val : 0.01f * val;
          _Float16 h = (_Float16)val;
          Uh.h[i] = h;
          Ul.h[i] = (_Float16)((val - (float)h) * 2048.0f);
        }
        size_t off = (((size_t)n * 16 + co16) * P2304 + pg) * 16 + col;
        *(uint2*)(yh + off) = Uh.u;
        *(uint2*)(yl + off) = Ul.u;
      }
    }
  }
}

// ---------------- shared MFMA compute macro (256-thread lds kernels) ------
#define COMPUTE_M(CUR, KF)                                                    \
  {                                                                           \
    const int ct0 = (g & 1) * 2, pt0 = (g >> 1) * 2;                          \
    half8 fAh[2], fAl[2], fBh[2], fBl[2];                                     \
    _Pragma("unroll")                                                         \
    for (int a = 0; a < 2; ++a){                                              \
      fAh[a] = *(half8*)&Abuf[CUR][KF][0][(ct0 + a) * 512 + lam * 8];         \
      fAl[a] = *(half8*)&Abuf[CUR][KF][1][(ct0 + a) * 512 + lam * 8];         \
      fBh[a] = *(half8*)&Bbuf[CUR][KF][0][(pt0 + a) * 512 + lam * 8];         \
      fBl[a] = *(half8*)&Bbuf[CUR][KF][1][(pt0 + a) * 512 + lam * 8];         \
    }                                                                         \
    _Pragma("unroll")                                                         \
    for (int a = 0; a < 2; ++a)                                               \
      _Pragma("unroll")                                                       \
      for (int b = 0; b < 2; ++b){                                            \
        acc_hh[a][b] = __builtin_amdgcn_mfma_f32_32x32x16_f16(                \
            fAh[a], fBh[b], acc_hh[a][b], 0, 0, 0);                           \
        acc_x[a][b] = __builtin_amdgcn_mfma_f32_32x32x16_f16(                 \
            fAh[a], fBl[b], acc_x[a][b], 0, 0, 0);                            \
        acc_x[a][b] = __builtin_amdgcn_mfma_f32_32x32x16_f16(                 \
            fAl[a], fBh[b], acc_x[a][b], 0, 0, 0);                            \
      }                                                                       \
  }

// ---------------- FAST conv2: 1x1 over [co16][p][16] split-f16 y ----------
// M=128co, N=2304p, K=256, BK=32 -> S=8 stages (r8 config, unchanged).
__global__ __launch_bounds__(256, 2) void conv2_lds_kernel(
    const u16* __restrict__ yh, const u16* __restrict__ yl,
    const uint4* __restrict__ Wh, const uint4* __restrict__ Wl,
    float* __restrict__ out)
{
  __shared__ _Float16 Abuf[2][2][2][2048];
  __shared__ _Float16 Bbuf[2][2][2][2048];
  const int t = threadIdx.x;
  const int lam = t & 63;
  const int g = t >> 6;

  const int pt_blk = blockIdx.x % 18;
  const int n = blockIdx.x / 18;
  const int pbase = pt_blk * 128;
  const int khi = lam >> 5;
  const int p = pbase + (g << 5) + (lam & 31);
  const u16* yh_n = yh + (size_t)n * 589824;     // 16*2304*16
  const u16* yl_n = yl + (size_t)n * 589824;

  const int S = 8;

  f32x16 acc_hh[2][2], acc_x[2][2];
#pragma unroll
  for (int a = 0; a < 2; ++a)
#pragma unroll
    for (int b = 0; b < 2; ++b){
#pragma unroll
      for (int e = 0; e < 16; ++e){ acc_hh[a][b][e] = 0.f; acc_x[a][b][e] = 0.f; }
    }

#define ISSUE2(SV, BUF)                                                       \
  {                                                                           \
    int s_ = (SV);                                                            \
    int k0_ = 2 * s_;                                                         \
    _Pragma("unroll")                                                         \
    for (int kf = 0; kf < 2; ++kf){                                           \
      int fg_ = (k0_ + kf) * 4 + g;                                           \
      gll16(Wh + fg_ * 64 + lam, &Abuf[BUF][kf][0][t * 8]);                   \
      gll16(Wl + fg_ * 64 + lam, &Abuf[BUF][kf][1][t * 8]);                   \
    }                                                                         \
    _Pragma("unroll")                                                         \
    for (int kf = 0; kf < 2; ++kf){                                           \
      size_t o_ = ((size_t)(k0_ + kf) * P2304 + p) * 16 + (khi << 3);         \
      gll16(yh_n + o_, &Bbuf[BUF][kf][0][t * 8]);                             \
      gll16(yl_n + o_, &Bbuf[BUF][kf][1][t * 8]);                             \
    }                                                                         \
  }

  ISSUE2(0, 0);
  ISSUE2(1, 1);

  for (int s = 0; s < S - 1; ++s){
    WAITV8;
    BARSB;
    __builtin_amdgcn_s_setprio(1);
    COMPUTE_M(s & 1, 0);
    COMPUTE_M(s & 1, 1);
    __builtin_amdgcn_s_setprio(0);
    if (s + 2 < S){
      BARSB;
      ISSUE2(s + 2, s & 1);
    }
  }
  WAITV0;
  BARSB;
  __builtin_amdgcn_s_setprio(1);
  COMPUTE_M((S - 1) & 1, 0);
  COMPUTE_M((S - 1) & 1, 1);
  __builtin_amdgcn_s_setprio(0);
#undef ISSUE2

  // epilogue: combine hi/lo, store x2 f32 [n][co][p]
#pragma unroll
  for (int a = 0; a < 2; ++a){
    const int ctile = (g & 1) * 2 + a;
#pragma unroll
    for (int b = 0; b < 2; ++b){
      const int ptile = (g >> 1) * 2 + b;
      const int pg = pbase + ptile * 32 + (lam & 31);
#pragma unroll
      for (int rg = 0; rg < 16; ++rg){
        const int row = (rg & 3) + 8 * (rg >> 2) + 4 * khi;
        const int co = ctile * 32 + row;
        float val = acc_hh[a][b][rg] + acc_x[a][b][rg] * (1.0f / 2048.0f);
        out[((size_t)n * C2 + co) * P2304 + pg] = val;
      }
    }
  }
}

// ---------------- FALLBACK split-f16 MFMA conv (3x3 SAME or 1x1) ----------
template<int R, int CPT, int COTN, bool BN>
__global__ __launch_bounds__(256, 2) void conv_mfma_kernel(
    const float* __restrict__ in, const uint4* __restrict__ Wh, const uint4* __restrict__ Wl,
    const float* __restrict__ s1, const float* __restrict__ t1, float* __restrict__ out)
{
  __shared__ _Float16 Abuf[2][2][2][2048];
  __shared__ _Float16 Bbuf[2][2][2][2048];
  const int t = threadIdx.x;
  const int lam = t & 63;
  const int g = t >> 6;

  int n, pt_blk, cot;
  if (COTN == 2){
    int xcd = blockIdx.x & 7;
    int rest = blockIdx.x >> 3;
    n = xcd * 4 + rest / 36;
    int inner = rest % 36;
    pt_blk = inner % 18;
    cot = inner / 18;
  } else {
    pt_blk = blockIdx.x % 18;
    cot = 0;
    n = blockIdx.x / 18;
  }
  const int pbase = pt_blk * 128;
  const int cobase = cot * 128;

  const int khi = lam >> 5;
  const int pp = (g << 5) + (lam & 31);
  const int p = pbase + pp;
  const int ph = p / 48, pw = p - ph * 48;
  const float* in_n = in + (size_t)n * CPT * P2304;

  const int S = (R * CPT) / 32;
  const int KTPT = CPT / 16;

  f32x16 acc_hh[2][2], acc_x[2][2];
#pragma unroll
  for (int a = 0; a < 2; ++a)
#pragma unroll
    for (int b = 0; b < 2; ++b){
#pragma unroll
      for (int e = 0; e < 16; ++e){ acc_hh[a][b][e] = 0.f; acc_x[a][b][e] = 0.f; }
    }

  uint4 rAh[2], rAl[2];
  float rB[16];
  bool vmask;

#define ISSUE(SV)                                                             \
  {                                                                           \
    int s_ = (SV);                                                            \
    _Pragma("unroll")                                                         \
    for (int kf = 0; kf < 2; ++kf){                                           \
      int fi = (((2 * s_ + kf) * COTN + cot) * 4 + g) * 64 + lam;             \
      rAh[kf] = Wh[fi];                                                       \
      rAl[kf] = Wl[fi];                                                       \
    }                                                                         \
    int r_ = (R == 1) ? 0 : ((2 * s_) / KTPT);                                \
    int cbase_ = ((2 * s_) % KTPT) * 16;                                      \
    int dh_ = (R == 1) ? 0 : (r_ / 3 - 1);                                    \
    int dw_ = (R == 1) ? 0 : (r_ - (r_ / 3) * 3 - 1);                         \
    int hh_ = ph + dh_, ww_ = pw + dw_;                                       \
    vmask = ((unsigned)hh_ < 48u) & ((unsigned)ww_ < 48u);                    \
    int hc_ = min(max(hh_, 0), 47), wc_ = min(max(ww_, 0), 47);               \
    const float* src_ = in_n + hc_ * 48 + wc_                                 \
                        + (size_t)(cbase_ + khi * 8) * P2304;                 \
    _Pragma("unroll")                                                         \
    for (int kf = 0; kf < 2; ++kf)                                            \
      _Pragma("unroll")                                                       \
      for (int j = 0; j < 8; ++j)                                             \
        rB[kf * 8 + j] = src_[(kf * 16 + j) * P2304];                         \
  }

#define STASH(NXT)                                                            \
  {                                                                           \
    _Pragma("unroll")                                                         \
    for (int kf = 0; kf < 2; ++kf){                                           \
      *(uint4*)&Abuf[NXT][kf][0][t * 8] = rAh[kf];                            \
      *(uint4*)&Abuf[NXT][kf][1][t * 8] = rAl[kf];                            \
      half8 vh, vl;                                                           \
      _Pragma("unroll")                                                       \
      for (int j = 0; j < 8; ++j){                                            \
        float v = vmask ? rB[kf * 8 + j] : 0.0f;                              \
        _Float16 h = (_Float16)v;                                             \
        vh[j] = h;                                                            \
        vl[j] = (_Float16)((v - (float)h) * 2048.0f);                         \
      }                                                                       \
      *(half8*)&Bbuf[NXT][kf][0][t * 8] = vh;                                 \
      *(half8*)&Bbuf[NXT][kf][1][t * 8] = vl;                                 \
    }                                                                         \
  }

  ISSUE(0);
  STASH(0);
  __syncthreads();

  for (int s = 0; s < S; ++s){
    const int cur = s & 1, nxt = cur ^ 1;
    const bool more = (s + 1 < S);
    if (more) ISSUE(s + 1);
    COMPUTE_M(cur, 0);
    if (more) STASH(nxt);
    COMPUTE_M(cur, 1);
    __syncthreads();
  }
#undef ISSUE
#undef STASH

  const int M = COTN * 128;
#pragma unroll
  for (int a = 0; a < 2; ++a){
    const int ctile = (g & 1) * 2 + a;
#pragma unroll
    for (int b = 0; b < 2; ++b){
      const int ptile = (g >> 1) * 2 + b;
      const int pg = pbase + ptile * 32 + (lam & 31);
#pragma unroll
      for (int rg = 0; rg < 16; ++rg){
        const int row = (rg & 3) + 8 * (rg >> 2) + 4 * (lam >> 5);
        const int co = cobase + ctile * 32 + row;
        float val = acc_hh[a][b][rg] + acc_x[a][b][rg] * (1.0f / 2048.0f);
        if (BN){
          val = val * s1[co] + t1[co];
          val = val > 0.f ? val : 0.01f * val;
        }
        out[((size_t)n * M + co) * P2304 + pg] = val;
      }
    }
  }
}

// ---------------- x_ave (mean over 2304 positions per (n,c)) ----------------
__global__ void xave_kernel(const float* __restrict__ x2, float* __restrict__ xave){
  __shared__ float red[4];
  int nc = blockIdx.x, t = threadIdx.x;
  const float* row = x2 + nc * P2304;
  float s = 0.f;
#pragma unroll
  for (int i = 0; i < 9; i++) s += row[t + 256 * i];
  float w = wredSum(s);
  if ((t & 63) == 0) red[t >> 6] = w;
  __syncthreads();
  if (t == 0) xave[nc] = (red[0] + red[1] + red[2] + red[3]) * (1.0f / 2304.0f);
}

__global__ void xan_kernel(const float* __restrict__ xave, float* __restrict__ xan){
  __shared__ float red[2];
  int n = blockIdx.x, t = threadIdx.x; // 128 threads
  float v = xave[n * 128 + t];
  float w = wredSum(v * v);
  if ((t & 63) == 0) red[t >> 6] = w;
  __syncthreads();
  float norm = fmaxf(sqrtf(red[0] + red[1]), 1e-12f);
  xan[n * 128 + t] = v / norm;
}

__global__ void cos_kernel(const float* __restrict__ x2, const float* __restrict__ xan,
                           float* __restrict__ cosb){
  int idx = blockIdx.x * 256 + threadIdx.x;
  if (idx >= N_IMG * P2304) return;
  int n = idx / P2304;
  int p = idx - n * P2304;
  const float* xp = x2 + n * C2 * P2304 + p;
  const float* an = xan + n * 128;
  float dot = 0.f, ss = 0.f;
  for (int c = 0; c < 128; c++){
    float v = xp[c * P2304];
    dot += an[c] * v;
    ss  += v * v;
  }
  cosb[idx] = dot / fmaxf(sqrtf(ss), 1e-12f);
}

// ---------------- LBP code + normalization + qlv ----------------
__global__ void lbp_kernel(const float* __restrict__ cosb, float* __restrict__ code,
                           float* __restrict__ qlv){
  __shared__ float red[4];
  int n = blockIdx.x;
  int l = threadIdx.x;           // 256 positions, l = ir*16+ic
  int ir = l >> 4, ic = l & 15;
  const float* cn = cosb + n * P2304;
  float cs4 = cn[(16 + ir) * 48 + (16 + ic)];
  const float wts[9] = {1.f, 2.f, 4.f, 8.f, 0.f, 16.f, 32.f, 64.f, 128.f};
  float codev = 0.f;
#pragma unroll
  for (int j = 0; j < 9; j++){
    int jr = j / 3, jc = j - 3 * (j / 3);
    float vv = cn[(jr * 16 + ir) * 48 + (jc * 16 + ic)];
    if (vv > cs4) codev += wts[j];
  }
  float w;
  w = wredMin(codev);
  if ((l & 63) == 0) red[l >> 6] = w;
  __syncthreads();
  float mn = fminf(fminf(red[0], red[1]), fminf(red[2], red[3]));
  __syncthreads();
  w = wredMax(codev);
  if ((l & 63) == 0) red[l >> 6] = w;
  __syncthreads();
  float mx = fmaxf(fmaxf(red[0], red[1]), fmaxf(red[2], red[3]));
  __syncthreads();
  float cd = (codev - mn) / (mx - mn);
  w = wredMin(cd);
  if ((l & 63) == 0) red[l >> 6] = w;
  __syncthreads();
  float cmin = fminf(fminf(red[0], red[1]), fminf(red[2], red[3]));
  __syncthreads();
  w = wredMax(cd);
  if ((l & 63) == 0) red[l >> 6] = w;
  __syncthreads();
  float cmax = fmaxf(fmaxf(red[0], red[1]), fmaxf(red[2], red[3]));
  code[n * 256 + l] = cd;
  if (l < 128){
    float tmp = (float)(2 * l + 1) * (1.0f / 256.0f);
    qlv[n * 128 + l] = tmp * (cmax - cmin) + cmin;
  }
}

__global__ void quant_kernel(const float* __restrict__ code, const float* __restrict__ qlv,
                             float* __restrict__ quantT){
  __shared__ float cs[256];
  __shared__ float qs[128];
  int n = blockIdx.x, t = threadIdx.x;
  cs[t] = code[n * 256 + t];
  if (t < 128) qs[t] = qlv[n * 128 + t];
  __syncthreads();
  float thr = 1.0f - (qs[1] - qs[0]);
  float* dst = quantT + n * LEV * 256;
#pragma unroll 4
  for (int i = 0; i < 128; i++){
    int v = t + 256 * i;
    int lv = v >> 8;
    int p = v & 255;
    float qq = 1.0f - fabsf(qs[lv] - cs[p]);
    dst[v] = (qq > thr) ? qq : 0.f;
  }
}

// sta phase A: rowsum per (n,lev), coalesced float4 reads, wave per row
__global__ void sta_rows_kernel(const float* __restrict__ quantT, float* __restrict__ raw){
  int b = blockIdx.x;                 // 1024 = 32n * 32
  int t = threadIdx.x;                // 256 = 4 waves
  int n = b >> 5;
  int row = (b & 31) * 4 + (t >> 6);  // wave -> row
  int lane = t & 63;
  const float* src = quantT + ((size_t)(n * LEV + row)) * 256 + lane * 4;
  float4 v = *(const float4*)src;
  float s = v.x + v.y + v.z + v.w;
  s = wredSum(s);
  if (lane == 0) raw[n * 128 + row] = s;
}

// sta phase B: normalize by per-n total
__global__ void sta_norm_kernel(const float* __restrict__ raw, float* __restrict__ sta){
  __shared__ float red[2];
  int n = blockIdx.x, t = threadIdx.x; // 128
  float v = raw[n * 128 + t];
  float w = wredSum(v);
  if ((t & 63) == 0) red[t >> 6] = w;
  __syncthreads();
  sta[n * 128 + t] = v / (red[0] + red[1]);
}

__global__ void h1_kernel(const float* __restrict__ f1w, const float* __restrict__ qlv,
                          const float* __restrict__ sta, float* __restrict__ h1){
  int idx = blockIdx.x * 256 + threadIdx.x;
  if (idx >= N_IMG * 64 * 128) return;
  int l = idx & 127;
  int n = idx >> 13;
  int o = (idx >> 7) & 63;
  float a = f1w[o * 2] * qlv[n * 128 + l] + f1w[o * 2 + 1] * sta[n * 128 + l];
  h1[idx] = a > 0.f ? a : 0.01f * a;
}

__global__ void gemm_w_kernel(const float* __restrict__ Wm, const float* __restrict__ B,
                              float* __restrict__ Cout, int Cdim, int O, int total, int mode,
                              const float* __restrict__ g, const float* __restrict__ bb,
                              const float* __restrict__ mm, const float* __restrict__ vv){
  int idx = blockIdx.x * 256 + threadIdx.x;
  if (idx >= total) return;
  int per_n = (O >> 2) << 7;
  int n = idx / per_n;
  int rem = idx - n * per_n;
  int o0 = (rem >> 7) << 2;
  int l = rem & 127;
  const float* Bn = B + (n * Cdim) * 128 + l;
  const float* w0 = Wm + (o0 + 0) * Cdim;
  const float* w1 = Wm + (o0 + 1) * Cdim;
  const float* w2 = Wm + (o0 + 2) * Cdim;
  const float* w3 = Wm + (o0 + 3) * Cdim;
  float a0 = 0, a1 = 0, a2 = 0, a3 = 0;
  for (int c = 0; c < Cdim; c++){
    float bv = Bn[c * 128];
    a0 += w0[c] * bv; a1 += w1[c] * bv; a2 += w2[c] * bv; a3 += w3[c] * bv;
  }
  float av[4] = {a0, a1, a2, a3};
#pragma unroll
  for (int j = 0; j < 4; j++){
    int o = o0 + j;
    float val = av[j];
    if (mode == 1){
      float s = g[o] * (1.0f / sqrtf(vv[o] + 1e-5f));
      val = (val - mm[o]) * s + bb[o];
      val = fmaxf(val, 0.f);
    }
    Cout[(n * O + o) * 128 + l] = val;
  }
}

// fused k/q/v projections (one launch, shared B in L2)
__global__ void gemm_kqv_kernel(const float* __restrict__ kW, const float* __restrict__ qW,
                                const float* __restrict__ vW, const float* __restrict__ B,
                                float* __restrict__ kO, float* __restrict__ qO,
                                float* __restrict__ vO){
  int idx = blockIdx.x * 256 + threadIdx.x;   // 3 * 262144
  int sel = idx >> 18;
  int rem = idx & 262143;
  const float* Wm = (sel == 0) ? kW : (sel == 1) ? qW : vW;
  float* Cout     = (sel == 0) ? kO : (sel == 1) ? qO : vO;
  int n = rem >> 13;
  int r2 = rem & 8191;
  int o0 = (r2 >> 7) << 2;
  int l = r2 & 127;
  const float* Bn = B + (n * 256) * 128 + l;
  const float* w0 = Wm + (o0 + 0) * 256;
  const float* w1 = Wm + (o0 + 1) * 256;
  const float* w2 = Wm + (o0 + 2) * 256;
  const float* w3 = Wm + (o0 + 3) * 256;
  float a0 = 0, a1 = 0, a2 = 0, a3 = 0;
  for (int c = 0; c < 256; c++){
    float bv = Bn[c * 128];
    a0 += w0[c] * bv; a1 += w1[c] * bv; a2 += w2[c] * bv; a3 += w3[c] * bv;
  }
  float* dst = Cout + (n * 256 + o0) * 128 + l;
  dst[0] = a0; dst[128] = a1; dst[256] = a2; dst[384] = a3;
}

__global__ void concat_kernel(const float* __restrict__ h2, const float* __restrict__ xave,
                              float* __restrict__ s){
  int idx = blockIdx.x * 256 + threadIdx.x;
  if (idx >= N_IMG * 256 * 128) return;
  int l = idx & 127;
  int c = (idx >> 7) & 255;
  int n = idx >> 15;
  s[idx] = (c < 128) ? h2[(n * 128 + c) * 128 + l] : xave[n * 128 + (c - 128)];
}

__global__ void attn_sc_kernel(const float* __restrict__ k, const float* __restrict__ q,
                               float* __restrict__ sc){
  int idx = blockIdx.x * 256 + threadIdx.x;
  if (idx >= N_IMG * 32 * 128) return;
  int m = idx & 127;
  int l0 = ((idx >> 7) & 31) << 2;
  int n = idx >> 12;
  const float* kn = k + n * 256 * 128;
  const float* qn = q + n * 256 * 128 + m;
  float a0 = 0, a1 = 0, a2 = 0, a3 = 0;
  for (int c = 0; c < 256; c++){
    float qv = qn[c * 128];
    const float* kr = kn + c * 128 + l0;
    a0 += kr[0] * qv; a1 += kr[1] * qv; a2 += kr[2] * qv; a3 += kr[3] * qv;
  }
  float* dst = sc + (n * 128 + l0) * 128 + m;
  dst[0] = a0; dst[128] = a1; dst[256] = a2; dst[384] = a3;
}

__global__ void softmax_kernel(float* __restrict__ sc){
  __shared__ float red[2];
  int row = blockIdx.x;
  int t = threadIdx.x; // 128
  float v = sc[row * 128 + t];
  float w = wredMax(v);
  if ((t & 63) == 0) red[t >> 6] = w;
  __syncthreads();
  float mx = fmaxf(red[0], red[1]);
  float e = expf(v - mx);
  float s = wredSum(e);
  __syncthreads();
  if ((t & 63) == 0) red[t >> 6] = s;
  __syncthreads();
  sc[row * 128 + t] = e / (red[0] + red[1]);
}

__global__ void transpose_sc_kernel(const float* __restrict__ sc, float* __restrict__ scT){
  int idx = blockIdx.x * 256 + threadIdx.x;
  if (idx >= N_IMG * 128 * 128) return;
  int l = idx & 127;
  int m = (idx >> 7) & 127;
  int n = idx >> 14;
  scT[idx] = sc[(n * 128 + l) * 128 + m];
}

__global__ void attn_f_kernel(const float* __restrict__ vb, const float* __restrict__ scT,
                              float* __restrict__ f){
  int idx = blockIdx.x * 256 + threadIdx.x;
  if (idx >= N_IMG * 64 * 128) return;
  int l = idx & 127;
  int c0 = ((idx >> 7) & 63) << 2;
  int n = idx >> 13;
  const float* vn = vb + (n * 256 + c0) * 128;
  const float* sn = scT + n * 128 * 128 + l;
  float a0 = 0, a1 = 0, a2 = 0, a3 = 0;
  for (int m = 0; m < 128; m++){
    float sv = sn[m * 128];
    a0 += vn[m] * sv; a1 += vn[128 + m] * sv; a2 += vn[256 + m] * sv; a3 += vn[384 + m] * sv;
  }
  float* dst = f + (n * 256 + c0) * 128 + l;
  dst[0] = a0; dst[128] = a1; dst[256] = a2; dst[384] = a3;
}

__global__ void final_kernel(const float* __restrict__ g, const float* __restrict__ quantT,
                             float* __restrict__ outs){
  int idx = blockIdx.x * 256 + threadIdx.x;
  if (idx >= N_IMG * 64 * 256) return;
  int p = idx & 255;
  int c0 = ((idx >> 8) & 63) << 2;
  int n = idx >> 14;
  const float* gn = g + (n * 256 + c0) * 128;
  const float* qn = quantT + (n * LEV) * 256 + p;
  float a0 = 0, a1 = 0, a2 = 0, a3 = 0;
  for (int lv = 0; lv < 128; lv++){
    float qv = qn[lv * 256];
    a0 += gn[lv] * qv; a1 += gn[128 + lv] * qv; a2 += gn[256 + lv] * qv; a3 += gn[384 + lv] * qv;
  }
  float* dst = outs + (n * 256 + c0) * 256 + p;
  dst[0] = a0; dst[256] = a1; dst[512] = a2; dst[768] = a3;
}

__global__ void resize_kernel(const float* __restrict__ outs, float* __restrict__ dout){
  int idx = blockIdx.x * 256 + threadIdx.x;
  if (idx >= N_IMG * 256 * P2304) return;
  int ow = idx % 48;
  int tmp = idx / 48;
  int oh = tmp % 48;
  int nc = tmp / 48;
  const float* src = outs + nc * 256;
  float fy = oh * (15.0f / 47.0f);
  float fx = ow * (15.0f / 47.0f);
  int y0 = (int)fy;
  int x0 = (int)fx;
  int y1 = min(y0 + 1, 15);
  int x1 = min(x0 + 1, 15);
  float wy = fy - (float)y0;
  float wx = fx - (float)x0;
  float v00 = src[y0 * 16 + x0], v01 = src[y0 * 16 + x1];
  float v10 = src[y1 * 16 + x0], v11 = src[y1 * 16 + x1];
  dout[idx] = v00 * (1.f - wy) * (1.f - wx) + v01 * (1.f - wy) * wx
            + v10 * wy * (1.f - wx) + v11 * wy * wx;
}

// ---------------- launcher ----------------
extern "C" void kernel_launch(void* const* d_in, const int* in_sizes, int n_in,
                              void* d_out, int out_size, void* d_ws, size_t ws_size,
                              hipStream_t stream)
{
  const float* x       = (const float*)d_in[0];
  const float* conv1_w = (const float*)d_in[1];
  const float* bn1_g   = (const float*)d_in[2];
  const float* bn1_b   = (const float*)d_in[3];
  const float* bn1_m   = (const float*)d_in[4];
  const float* bn1_v   = (const float*)d_in[5];
  const float* conv2_w = (const float*)d_in[6];
  const float* f1_w    = (const float*)d_in[7];
  const float* f2_w    = (const float*)d_in[8];
  const float* f2_g    = (const float*)d_in[9];
  const float* f2_b    = (const float*)d_in[10];
  const float* f2_m    = (const float*)d_in[11];
  const float* f2_v    = (const float*)d_in[12];
  const float* out1_w  = (const float*)d_in[13];
  const float* out1_g  = (const float*)d_in[14];
  const float* out1_b  = (const float*)d_in[15];
  const float* out1_m  = (const float*)d_in[16];
  const float* out1_v  = (const float*)d_in[17];
  const float* k_w     = (const float*)d_in[18];
  const float* q_w     = (const float*)d_in[19];
  const float* v_w     = (const float*)d_in[20];
  const float* out_w   = (const float*)d_in[21];
  const float* out_g   = (const float*)d_in[22];
  const float* out_b   = (const float*)d_in[23];
  const float* out_m   = (const float*)d_in[24];
  const float* out_v   = (const float*)d_in[25];

  float* ws = (float*)d_ws;
  float* dout = (float*)d_out;

  // fixed region (same layout as baseline)
  float* w_y   = ws;                  // 18874368 f (fast path: yh/yl u16 pair)
  float* w_x2  = ws + 18874368;       // 9437184 f
  float* w_W1h = ws + 28311552;       // 589824
  float* w_W1l = ws + 28901376;       // 589824
  float* w_W2h = ws + 29491200;       // 16384
  float* w_W2l = ws + 29507584;       // 16384
  float* w_s1  = ws + 29523968;       // 256
  float* w_t1  = ws + 29524224;       // 256  => fixed total 29524480 f
  // small buffers reuse the y region (only written after conv2 consumed y)
  float* w_xave = w_y + 0;
  float* w_xan  = w_y + 4096;
  float* w_cos  = w_y + 8192;
  float* w_code = w_y + 81920;
  float* w_qlv  = w_y + 90112;
  float* w_sta  = w_y + 94208;
  float* w_quant= w_y + 98304;
  float* w_h1   = w_y + 1146880;
  float* w_h2   = w_y + 1409024;
  float* w_s    = w_y + 1933312;
  float* w_k    = w_y + 2981888;
  float* w_q    = w_y + 4030464;
  float* w_v    = w_y + 5079040;
  float* w_sc   = w_y + 6127616;
  float* w_scT  = w_y + 6651904;
  float* w_f    = w_y + 7176192;
  float* w_g    = w_y + 8224768;
  float* w_outs = w_y + 9273344;
  float* w_s2   = w_y + 11370496;
  float* w_raw  = w_y + 12419072;     // 4096 (sta rowsums)

  prep_w1_kernel<<<576, 256, 0, stream>>>(conv1_w, (uint4*)w_W1h, (uint4*)w_W1l);
  prep_w2_kernel<<<16, 256, 0, stream>>>(conv2_w, (uint4*)w_W2h, (uint4*)w_W2l);
  prep_bn_kernel<<<1, 256, 0, stream>>>(bn1_g, bn1_b, bn1_m, bn1_v, w_s1, w_t1);

  // --- conv1/conv2: fast path selection by available workspace ---
  const size_t BASE_F = 29524480;
  const size_t XPI_F  = 640000;                   // floats per image per array
  const size_t ws_f = ws_size / 4;
  int NCc = 0;
  if (ws_f >= BASE_F + 2 * 32 * XPI_F)      NCc = 32;
  else if (ws_f >= BASE_F + 2 * 16 * XPI_F) NCc = 16;

  if (NCc > 0){
    u16* w_xh = (u16*)(ws + BASE_F);
    u16* w_xl = w_xh + (size_t)NCc * 1280000;
    u16* w_yh = (u16*)w_y;                        // 18.87M u16 = 9437184 f
    u16* w_yl = (u16*)(w_y + 9437184);            // fills w_y region exactly
    const int nchunk = N_IMG / NCc;
    for (int c = 0; c < nchunk; ++c){
      int n0 = c * NCc;
      prep_x_kernel<<<NCc * 50, 256, 0, stream>>>(x, w_xh, w_xl, n0);
      if (NCc == 32)
        conv1_wide_kernel<32><<<576, 512, 0, stream>>>(
            w_xh, w_xl, (const uint4*)w_W1h, (const uint4*)w_W1l, w_s1, w_t1,
            w_yh, w_yl, n0);
      else
        conv1_wide_kernel<16><<<288, 512, 0, stream>>>(
            w_xh, w_xl, (const uint4*)w_W1h, (const uint4*)w_W1l, w_s1, w_t1,
            w_yh, w_yl, n0);
    }
    conv2_lds_kernel<<<576, 256, 0, stream>>>(
        w_yh, w_yl, (const uint4*)w_W2h, (const uint4*)w_W2l, w_x2);
  } else {
    conv_mfma_kernel<9, 512, 2, true><<<1152, 256, 0, stream>>>(
        x, (const uint4*)w_W1h, (const uint4*)w_W1l, w_s1, w_t1, w_y);
    conv_mfma_kernel<1, 256, 1, false><<<576, 256, 0, stream>>>(
        w_y, (const uint4*)w_W2h, (const uint4*)w_W2l, w_s1, w_t1, w_x2);
  }

  xave_kernel<<<4096, 256, 0, stream>>>(w_x2, w_xave);
  xan_kernel<<<32, 128, 0, stream>>>(w_xave, w_xan);
  cos_kernel<<<288, 256, 0, stream>>>(w_x2, w_xan, w_cos);
  lbp_kernel<<<32, 256, 0, stream>>>(w_cos, w_code, w_qlv);
  quant_kernel<<<32, 256, 0, stream>>>(w_code, w_qlv, w_quant);
  sta_rows_kernel<<<1024, 256, 0, stream>>>(w_quant, w_raw);
  sta_norm_kernel<<<32, 128, 0, stream>>>(w_raw, w_sta);
  h1_kernel<<<1024, 256, 0, stream>>>(f1_w, w_qlv, w_sta, w_h1);
  gemm_w_kernel<<<512, 256, 0, stream>>>(f2_w, w_h1, w_h2, 64, 128, N_IMG * 32 * 128, 1,
                                         f2_g, f2_b, f2_m, f2_v);
  concat_kernel<<<4096, 256, 0, stream>>>(w_h2, w_xave, w_s);
  gemm_w_kernel<<<1024, 256, 0, stream>>>(out1_w, w_s, w_s2, 256, 256, N_IMG * 64 * 128, 1,
                                          out1_g, out1_b, out1_m, out1_v);
  gemm_kqv_kernel<<<3072, 256, 0, stream>>>(k_w, q_w, v_w, w_s2, w_k, w_q, w_v);
  attn_sc_kernel<<<512, 256, 0, stream>>>(w_k, w_q, w_sc);
  softmax_kernel<<<4096, 128, 0, stream>>>(w_sc);
  transpose_sc_kernel<<<2048, 256, 0, stream>>>(w_sc, w_scT);
  attn_f_kernel<<<1024, 256, 0, stream>>>(w_v, w_scT, w_f);
  gemm_w_kernel<<<1024, 256, 0, stream>>>(out_w, w_f, w_g, 256, 256, N_IMG * 64 * 128, 1,
                                          out_g, out_b, out_m, out_v);
  final_kernel<<<2048, 256, 0, stream>>>(w_g, w_quant, w_outs);
  resize_kernel<<<73728, 256, 0, stream>>>(w_outs, dout);
}

// Round 10
// 1485.283 us; speedup vs baseline: 1.0682x; 1.0682x over previous
//
#include <hip/hip_runtime.h>
#include <math.h>

#define N_IMG 32
#define P2304 2304
#define CIN 512
#define CMID 256
#define C2 128
#define LEV 128

typedef _Float16 half8 __attribute__((ext_vector_type(8)));
typedef float f32x16 __attribute__((ext_vector_type(16)));
typedef unsigned short u16;
typedef unsigned int u32;

// ---------------- wave/block reduction helpers (wave = 64) ----------------
__device__ __forceinline__ float wredSum(float v){
#pragma unroll
  for (int o = 32; o > 0; o >>= 1) v += __shfl_down(v, o, 64);
  return v;
}
__device__ __forceinline__ float wredMax(float v){
#pragma unroll
  for (int o = 32; o > 0; o >>= 1) v = fmaxf(v, __shfl_down(v, o, 64));
  return v;
}
__device__ __forceinline__ float wredMin(float v){
#pragma unroll
  for (int o = 32; o > 0; o >>= 1) v = fminf(v, __shfl_down(v, o, 64));
  return v;
}

// async 16B global -> LDS (wave-uniform LDS base + lane*16)
__device__ __forceinline__ void gll16(const void* g, void* l){
  __builtin_amdgcn_global_load_lds(
      (const __attribute__((address_space(1))) void*)g,
      (__attribute__((address_space(3))) void*)l, 16, 0, 0);
}

// ---------------- weight prepack: split f32 -> (hi, lo*2^11) f16 frags ----
// Fragment order: frag index fi = ((kt*COTN + cot)*4 + c32)*64 + lam,
// holding 8 f16: element j is W[co = cot*128 + c32*32 + (lam&31)]
//                             [k  = kt*16 + (lam>>5)*8 + j]
__global__ void prep_w1_kernel(const float* __restrict__ w1,
                               uint4* __restrict__ Wh, uint4* __restrict__ Wl){
  int fid = blockIdx.x * 256 + threadIdx.x;     // 147456 frags
  int lam = fid & 63;
  int c32 = (fid >> 6) & 3;
  int cot = (fid >> 8) & 1;
  int kt  = fid >> 9;                           // 0..287
  int co = cot * 128 + c32 * 32 + (lam & 31);
  half8 vh, vl;
#pragma unroll
  for (int j = 0; j < 8; ++j){
    int k = kt * 16 + ((lam >> 5) << 3) + j;    // 0..4607
    int r = k >> 9;                             // tap
    int ci = k & 511;
    float v = w1[co * (CIN * 9) + ci * 9 + r];
    _Float16 h = (_Float16)v;
    vh[j] = h;
    vl[j] = (_Float16)((v - (float)h) * 2048.0f);
  }
  Wh[fid] = *(uint4*)&vh;
  Wl[fid] = *(uint4*)&vl;
}

__global__ void prep_w2_kernel(const float* __restrict__ w2,
                               uint4* __restrict__ Wh, uint4* __restrict__ Wl){
  int fid = blockIdx.x * 256 + threadIdx.x;     // 4096 frags
  int lam = fid & 63;
  int c32 = (fid >> 6) & 3;
  int kt  = fid >> 8;                           // 0..15
  int co = c32 * 32 + (lam & 31);
  half8 vh, vl;
#pragma unroll
  for (int j = 0; j < 8; ++j){
    int k = kt * 16 + ((lam >> 5) << 3) + j;    // 0..255
    float v = w2[co * CMID + k];
    _Float16 h = (_Float16)v;
    vh[j] = h;
    vl[j] = (_Float16)((v - (float)h) * 2048.0f);
  }
  Wh[fid] = *(uint4*)&vh;
  Wl[fid] = *(uint4*)&vl;
}

// s1 = g/sqrt(v+eps), t1 = b - m*s1  (bn folded to y*s1 + t1)
__global__ void prep_bn_kernel(const float* __restrict__ g1, const float* __restrict__ b1,
                               const float* __restrict__ m1, const float* __restrict__ v1,
                               float* __restrict__ s1, float* __restrict__ t1){
  int c = threadIdx.x;  // 256
  float s = g1[c] * (1.0f / sqrtf(v1[c] + 1e-5f));
  s1[c] = s;
  t1[c] = b1[c] - m1[c] * s;
}

// ---------------- FAST PATH: transpose+pad+split x (ck-chunked layout) ----
__global__ void prep_x_kernel(const float* __restrict__ x,
                              u16* __restrict__ xh, u16* __restrict__ xl,
                              int n0){
  __shared__ float tile[128 * 49];
  const int t = threadIdx.x;
  const int b = blockIdx.x;
  const int n_loc = b / 50;
  const int hp = b - n_loc * 50;
  const int n = n0 + n_loc;
  const int h = hp - 1;
  const bool vrow = (h >= 0) && (h < 48);
  const size_t base_n = (size_t)n_loc * 1280000;   // 32*2500*16 u16 per image
  for (int cc = 0; cc < 4; ++cc){                  // channels cc*128..+128
    if (vrow){
      const float* src = x + (((size_t)n * 512 + cc * 128) * 48 + h) * 48;
#pragma unroll
      for (int i = 0; i < 24; ++i){
        int idx = t + 256 * i;            // 6144 = 128c x 48w
        int w = idx % 48;
        int c = idx / 48;
        tile[c * 49 + w] = src[(size_t)c * 2304 + w];
      }
    }
    __syncthreads();
    for (int i = 0; i < 13; ++i){
      int idx = t + 256 * i;
      if (idx < 3200){
        int ck_loc = idx / 400;           // 0..7
        int rem = idx - ck_loc * 400;
        int wp = rem >> 3;                // 0..49
        int clp = rem & 7;                // channel pair within 16
        int w = wp - 1;
        int c_loc = ck_loc * 16 + clp * 2;
        float v0 = 0.f, v1 = 0.f;
        if (vrow && (unsigned)w < 48u){
          v0 = tile[c_loc * 49 + w];
          v1 = tile[(c_loc + 1) * 49 + w];
        }
        _Float16 h0 = (_Float16)v0, h1 = (_Float16)v1;
        _Float16 l0 = (_Float16)((v0 - (float)h0) * 2048.0f);
        _Float16 l1 = (_Float16)((v1 - (float)h1) * 2048.0f);
        union { _Float16 hh[2]; u32 uu; } ph, pl;
        ph.hh[0] = h0; ph.hh[1] = h1;
        pl.hh[0] = l0; pl.hh[1] = l1;
        size_t off = base_n + ((size_t)(cc * 8 + ck_loc) * 2500
                               + hp * 50 + wp) * 16 + clp * 2;  // u16 idx
        *(u32*)(xh + off) = ph.uu;
        *(u32*)(xl + off) = pl.uu;
      }
    }
    __syncthreads();
  }
}

// ---------------- shared MFMA compute macro (BK=32 lds conv kernels) ------
#define COMPUTE_M(CUR, KF)                                                    \
  {                                                                           \
    const int ct0 = (g & 1) * 2, pt0 = (g >> 1) * 2;                          \
    half8 fAh[2], fAl[2], fBh[2], fBl[2];                                     \
    _Pragma("unroll")                                                         \
    for (int a = 0; a < 2; ++a){                                              \
      fAh[a] = *(half8*)&Abuf[CUR][KF][0][(ct0 + a) * 512 + lam * 8];         \
      fAl[a] = *(half8*)&Abuf[CUR][KF][1][(ct0 + a) * 512 + lam * 8];         \
      fBh[a] = *(half8*)&Bbuf[CUR][KF][0][(pt0 + a) * 512 + lam * 8];         \
      fBl[a] = *(half8*)&Bbuf[CUR][KF][1][(pt0 + a) * 512 + lam * 8];         \
    }                                                                         \
    _Pragma("unroll")                                                         \
    for (int a = 0; a < 2; ++a)                                               \
      _Pragma("unroll")                                                       \
      for (int b = 0; b < 2; ++b){                                            \
        acc_hh[a][b] = __builtin_amdgcn_mfma_f32_32x32x16_f16(                \
            fAh[a], fBh[b], acc_hh[a][b], 0, 0, 0);                           \
        acc_x[a][b] = __builtin_amdgcn_mfma_f32_32x32x16_f16(                 \
            fAh[a], fBl[b], acc_x[a][b], 0, 0, 0);                            \
        acc_x[a][b] = __builtin_amdgcn_mfma_f32_32x32x16_f16(                 \
            fAl[a], fBh[b], acc_x[a][b], 0, 0, 0);                            \
      }                                                                       \
  }

#define WAITV8  asm volatile("s_waitcnt vmcnt(8)"  ::: "memory")
#define WAITV0  asm volatile("s_waitcnt vmcnt(0)"  ::: "memory")
#define BARSB { __builtin_amdgcn_s_barrier(); __builtin_amdgcn_sched_barrier(0); }

// ---------------- FAST conv1: 3x3 SAME, BK=32, 2-buffer counted vmcnt -----
// (r8 configuration, best measured: conv1 = 667 us)
template<int NC>
__global__ __launch_bounds__(256, 2) void conv1_lds_kernel(
    const u16* __restrict__ xh, const u16* __restrict__ xl,
    const uint4* __restrict__ Wh, const uint4* __restrict__ Wl,
    const float* __restrict__ s1, const float* __restrict__ t1,
    u16* __restrict__ yh, u16* __restrict__ yl, int n0)
{
  __shared__ _Float16 Abuf[2][2][2][2048];
  __shared__ _Float16 Bbuf[2][2][2][2048];
  const int t = threadIdx.x;
  const int lam = t & 63;
  const int g = t >> 6;                 // wave id = staged c32 (A) / p32 (B) group

  const int xcd = blockIdx.x & 7;
  const int rest = blockIdx.x >> 3;
  const int NPX = NC / 8;
  const int n_loc = xcd * NPX + rest / 36;
  const int inner = rest % 36;
  const int pt_blk = inner % 18;
  const int cot = inner / 18;
  const int n = n0 + n_loc;

  const int pbase = pt_blk * 128;
  const int khi = lam >> 5;
  const int pp = (g << 5) + (lam & 31);
  const int p = pbase + pp;
  const int ph = p / 48, pw = p - ph * 48;
  const u16* xh_n = xh + (size_t)n_loc * 1280000;
  const u16* xl_n = xl + (size_t)n_loc * 1280000;

  const int S = 144;                    // 9*512/32 BK=32 stages

  f32x16 acc_hh[2][2], acc_x[2][2];
#pragma unroll
  for (int a = 0; a < 2; ++a)
#pragma unroll
    for (int b = 0; b < 2; ++b){
#pragma unroll
      for (int e = 0; e < 16; ++e){ acc_hh[a][b][e] = 0.f; acc_x[a][b][e] = 0.f; }
    }

#define ISSUE1(SV, BUF)                                                       \
  {                                                                           \
    int s_ = (SV);                                                            \
    int k0_ = 2 * s_;                                                         \
    _Pragma("unroll")                                                         \
    for (int kf = 0; kf < 2; ++kf){                                           \
      int fg_ = ((k0_ + kf) * 2 + cot) * 4 + g;                               \
      gll16(Wh + fg_ * 64 + lam, &Abuf[BUF][kf][0][t * 8]);                   \
      gll16(Wl + fg_ * 64 + lam, &Abuf[BUF][kf][1][t * 8]);                   \
    }                                                                         \
    int r_ = k0_ >> 5;                  /* tap 0..8 */                        \
    int ck0_ = k0_ & 31;                /* 16-ch chunk base (even) */         \
    int qpp_ = (ph + r_ / 3) * 50 + (pw + r_ % 3);   /* padded pos */         \
    _Pragma("unroll")                                                         \
    for (int kf = 0; kf < 2; ++kf){                                           \
      size_t o_ = ((size_t)(ck0_ + kf) * 2500 + qpp_) * 16 + (khi << 3);      \
      gll16(xh_n + o_, &Bbuf[BUF][kf][0][t * 8]);                             \
      gll16(xl_n + o_, &Bbuf[BUF][kf][1][t * 8]);                             \
    }                                                                         \
  }

  ISSUE1(0, 0);
  ISSUE1(1, 1);

  for (int s = 0; s < S - 1; ++s){
    WAITV8;
    BARSB;
    __builtin_amdgcn_s_setprio(1);
    COMPUTE_M(s & 1, 0);
    COMPUTE_M(s & 1, 1);
    __builtin_amdgcn_s_setprio(0);
    if (s + 2 < S){
      BARSB;
      ISSUE1(s + 2, s & 1);
    }
  }
  WAITV0;
  BARSB;
  __builtin_amdgcn_s_setprio(1);
  COMPUTE_M((S - 1) & 1, 0);
  COMPUTE_M((S - 1) & 1, 1);
  __builtin_amdgcn_s_setprio(0);
#undef ISSUE1

  // epilogue: combine hi/lo, bn+leaky, split f16, store y [n][co16][p][16]
  const int cobase = cot * 128;
#pragma unroll
  for (int a = 0; a < 2; ++a){
    const int ctile = (g & 1) * 2 + a;
#pragma unroll
    for (int b = 0; b < 2; ++b){
      const int ptile = (g >> 1) * 2 + b;
      const int pg = pbase + ptile * 32 + (lam & 31);
#pragma unroll
      for (int q = 0; q < 4; ++q){
        const int co0 = cobase + ctile * 32 + 8 * q + 4 * khi;
        const int co16 = co0 >> 4, col = co0 & 15;
        union { _Float16 h[4]; uint2 u; } Uh, Ul;
#pragma unroll
        for (int i = 0; i < 4; ++i){
          const int rg = 4 * q + i;
          const int co = co0 + i;
          float val = acc_hh[a][b][rg] + acc_x[a][b][rg] * (1.0f / 2048.0f);
          val = val * s1[co] + t1[co];
          val = val > 0.f ? val : 0.01f * val;
          _Float16 h = (_Float16)val;
          Uh.h[i] = h;
          Ul.h[i] = (_Float16)((val - (float)h) * 2048.0f);
        }
        size_t off = (((size_t)n * 16 + co16) * P2304 + pg) * 16 + col;
        *(uint2*)(yh + off) = Uh.u;
        *(uint2*)(yl + off) = Ul.u;
      }
    }
  }
}

// ---------------- FAST conv2: 1x1 over [co16][p][16] split-f16 y ----------
__global__ __launch_bounds__(256, 2) void conv2_lds_kernel(
    const u16* __restrict__ yh, const u16* __restrict__ yl,
    const uint4* __restrict__ Wh, const uint4* __restrict__ Wl,
    float* __restrict__ out)
{
  __shared__ _Float16 Abuf[2][2][2][2048];
  __shared__ _Float16 Bbuf[2][2][2][2048];
  const int t = threadIdx.x;
  const int lam = t & 63;
  const int g = t >> 6;

  const int pt_blk = blockIdx.x % 18;
  const int n = blockIdx.x / 18;
  const int pbase = pt_blk * 128;
  const int khi = lam >> 5;
  const int p = pbase + (g << 5) + (lam & 31);
  const u16* yh_n = yh + (size_t)n * 589824;     // 16*2304*16
  const u16* yl_n = yl + (size_t)n * 589824;

  const int S = 8;

  f32x16 acc_hh[2][2], acc_x[2][2];
#pragma unroll
  for (int a = 0; a < 2; ++a)
#pragma unroll
    for (int b = 0; b < 2; ++b){
#pragma unroll
      for (int e = 0; e < 16; ++e){ acc_hh[a][b][e] = 0.f; acc_x[a][b][e] = 0.f; }
    }

#define ISSUE2(SV, BUF)                                                       \
  {                                                                           \
    int s_ = (SV);                                                            \
    int k0_ = 2 * s_;                                                         \
    _Pragma("unroll")                                                         \
    for (int kf = 0; kf < 2; ++kf){                                           \
      int fg_ = (k0_ + kf) * 4 + g;                                           \
      gll16(Wh + fg_ * 64 + lam, &Abuf[BUF][kf][0][t * 8]);                   \
      gll16(Wl + fg_ * 64 + lam, &Abuf[BUF][kf][1][t * 8]);                   \
    }                                                                         \
    _Pragma("unroll")                                                         \
    for (int kf = 0; kf < 2; ++kf){                                           \
      size_t o_ = ((size_t)(k0_ + kf) * P2304 + p) * 16 + (khi << 3);         \
      gll16(yh_n + o_, &Bbuf[BUF][kf][0][t * 8]);                             \
      gll16(yl_n + o_, &Bbuf[BUF][kf][1][t * 8]);                             \
    }                                                                         \
  }

  ISSUE2(0, 0);
  ISSUE2(1, 1);

  for (int s = 0; s < S - 1; ++s){
    WAITV8;
    BARSB;
    __builtin_amdgcn_s_setprio(1);
    COMPUTE_M(s & 1, 0);
    COMPUTE_M(s & 1, 1);
    __builtin_amdgcn_s_setprio(0);
    if (s + 2 < S){
      BARSB;
      ISSUE2(s + 2, s & 1);
    }
  }
  WAITV0;
  BARSB;
  __builtin_amdgcn_s_setprio(1);
  COMPUTE_M((S - 1) & 1, 0);
  COMPUTE_M((S - 1) & 1, 1);
  __builtin_amdgcn_s_setprio(0);
#undef ISSUE2

  // epilogue: combine hi/lo, store x2 f32 [n][co][p]
#pragma unroll
  for (int a = 0; a < 2; ++a){
    const int ctile = (g & 1) * 2 + a;
#pragma unroll
    for (int b = 0; b < 2; ++b){
      const int ptile = (g >> 1) * 2 + b;
      const int pg = pbase + ptile * 32 + (lam & 31);
#pragma unroll
      for (int rg = 0; rg < 16; ++rg){
        const int row = (rg & 3) + 8 * (rg >> 2) + 4 * khi;
        const int co = ctile * 32 + row;
        float val = acc_hh[a][b][rg] + acc_x[a][b][rg] * (1.0f / 2048.0f);
        out[((size_t)n * C2 + co) * P2304 + pg] = val;
      }
    }
  }
}

// ---------------- FALLBACK split-f16 MFMA conv (3x3 SAME or 1x1) ----------
template<int R, int CPT, int COTN, bool BN>
__global__ __launch_bounds__(256, 2) void conv_mfma_kernel(
    const float* __restrict__ in, const uint4* __restrict__ Wh, const uint4* __restrict__ Wl,
    const float* __restrict__ s1, const float* __restrict__ t1, float* __restrict__ out)
{
  __shared__ _Float16 Abuf[2][2][2][2048];
  __shared__ _Float16 Bbuf[2][2][2][2048];
  const int t = threadIdx.x;
  const int lam = t & 63;
  const int g = t >> 6;

  int n, pt_blk, cot;
  if (COTN == 2){
    int xcd = blockIdx.x & 7;
    int rest = blockIdx.x >> 3;
    n = xcd * 4 + rest / 36;
    int inner = rest % 36;
    pt_blk = inner % 18;
    cot = inner / 18;
  } else {
    pt_blk = blockIdx.x % 18;
    cot = 0;
    n = blockIdx.x / 18;
  }
  const int pbase = pt_blk * 128;
  const int cobase = cot * 128;

  const int khi = lam >> 5;
  const int pp = (g << 5) + (lam & 31);
  const int p = pbase + pp;
  const int ph = p / 48, pw = p - ph * 48;
  const float* in_n = in + (size_t)n * CPT * P2304;

  const int S = (R * CPT) / 32;
  const int KTPT = CPT / 16;

  f32x16 acc_hh[2][2], acc_x[2][2];
#pragma unroll
  for (int a = 0; a < 2; ++a)
#pragma unroll
    for (int b = 0; b < 2; ++b){
#pragma unroll
      for (int e = 0; e < 16; ++e){ acc_hh[a][b][e] = 0.f; acc_x[a][b][e] = 0.f; }
    }

  uint4 rAh[2], rAl[2];
  float rB[16];
  bool vmask;

#define ISSUE(SV)                                                             \
  {                                                                           \
    int s_ = (SV);                                                            \
    _Pragma("unroll")                                                         \
    for (int kf = 0; kf < 2; ++kf){                                           \
      int fi = (((2 * s_ + kf) * COTN + cot) * 4 + g) * 64 + lam;             \
      rAh[kf] = Wh[fi];                                                       \
      rAl[kf] = Wl[fi];                                                       \
    }                                                                         \
    int r_ = (R == 1) ? 0 : ((2 * s_) / KTPT);                                \
    int cbase_ = ((2 * s_) % KTPT) * 16;                                      \
    int dh_ = (R == 1) ? 0 : (r_ / 3 - 1);                                    \
    int dw_ = (R == 1) ? 0 : (r_ - (r_ / 3) * 3 - 1);                         \
    int hh_ = ph + dh_, ww_ = pw + dw_;                                       \
    vmask = ((unsigned)hh_ < 48u) & ((unsigned)ww_ < 48u);                    \
    int hc_ = min(max(hh_, 0), 47), wc_ = min(max(ww_, 0), 47);               \
    const float* src_ = in_n + hc_ * 48 + wc_                                 \
                        + (size_t)(cbase_ + khi * 8) * P2304;                 \
    _Pragma("unroll")                                                         \
    for (int kf = 0; kf < 2; ++kf)                                            \
      _Pragma("unroll")                                                       \
      for (int j = 0; j < 8; ++j)                                             \
        rB[kf * 8 + j] = src_[(kf * 16 + j) * P2304];                         \
  }

#define STASH(NXT)                                                            \
  {                                                                           \
    _Pragma("unroll")                                                         \
    for (int kf = 0; kf < 2; ++kf){                                           \
      *(uint4*)&Abuf[NXT][kf][0][t * 8] = rAh[kf];                            \
      *(uint4*)&Abuf[NXT][kf][1][t * 8] = rAl[kf];                            \
      half8 vh, vl;                                                           \
      _Pragma("unroll")                                                       \
      for (int j = 0; j < 8; ++j){                                            \
        float v = vmask ? rB[kf * 8 + j] : 0.0f;                              \
        _Float16 h = (_Float16)v;                                             \
        vh[j] = h;                                                            \
        vl[j] = (_Float16)((v - (float)h) * 2048.0f);                         \
      }                                                                       \
      *(half8*)&Bbuf[NXT][kf][0][t * 8] = vh;                                 \
      *(half8*)&Bbuf[NXT][kf][1][t * 8] = vl;                                 \
    }                                                                         \
  }

  ISSUE(0);
  STASH(0);
  __syncthreads();

  for (int s = 0; s < S; ++s){
    const int cur = s & 1, nxt = cur ^ 1;
    const bool more = (s + 1 < S);
    if (more) ISSUE(s + 1);
    COMPUTE_M(cur, 0);
    if (more) STASH(nxt);
    COMPUTE_M(cur, 1);
    __syncthreads();
  }
#undef ISSUE
#undef STASH

  const int M = COTN * 128;
#pragma unroll
  for (int a = 0; a < 2; ++a){
    const int ctile = (g & 1) * 2 + a;
#pragma unroll
    for (int b = 0; b < 2; ++b){
      const int ptile = (g >> 1) * 2 + b;
      const int pg = pbase + ptile * 32 + (lam & 31);
#pragma unroll
      for (int rg = 0; rg < 16; ++rg){
        const int row = (rg & 3) + 8 * (rg >> 2) + 4 * (lam >> 5);
        const int co = cobase + ctile * 32 + row;
        float val = acc_hh[a][b][rg] + acc_x[a][b][rg] * (1.0f / 2048.0f);
        if (BN){
          val = val * s1[co] + t1[co];
          val = val > 0.f ? val : 0.01f * val;
        }
        out[((size_t)n * M + co) * P2304 + pg] = val;
      }
    }
  }
}

// ---------------- x_ave (mean over 2304 positions per (n,c)) ----------------
__global__ void xave_kernel(const float* __restrict__ x2, float* __restrict__ xave){
  __shared__ float red[4];
  int nc = blockIdx.x, t = threadIdx.x;
  const float* row = x2 + nc * P2304;
  float s = 0.f;
#pragma unroll
  for (int i = 0; i < 9; i++) s += row[t + 256 * i];
  float w = wredSum(s);
  if ((t & 63) == 0) red[t >> 6] = w;
  __syncthreads();
  if (t == 0) xave[nc] = (red[0] + red[1] + red[2] + red[3]) * (1.0f / 2304.0f);
}

__global__ void xan_kernel(const float* __restrict__ xave, float* __restrict__ xan){
  __shared__ float red[2];
  int n = blockIdx.x, t = threadIdx.x; // 128 threads
  float v = xave[n * 128 + t];
  float w = wredSum(v * v);
  if ((t & 63) == 0) red[t >> 6] = w;
  __syncthreads();
  float norm = fmaxf(sqrtf(red[0] + red[1]), 1e-12f);
  xan[n * 128 + t] = v / norm;
}

__global__ void cos_kernel(const float* __restrict__ x2, const float* __restrict__ xan,
                           float* __restrict__ cosb){
  int idx = blockIdx.x * 256 + threadIdx.x;
  if (idx >= N_IMG * P2304) return;
  int n = idx / P2304;
  int p = idx - n * P2304;
  const float* xp = x2 + n * C2 * P2304 + p;
  const float* an = xan + n * 128;
  float dot = 0.f, ss = 0.f;
  for (int c = 0; c < 128; c++){
    float v = xp[c * P2304];
    dot += an[c] * v;
    ss  += v * v;
  }
  cosb[idx] = dot / fmaxf(sqrtf(ss), 1e-12f);
}

// ---------------- LBP code + normalization + qlv ----------------
__global__ void lbp_kernel(const float* __restrict__ cosb, float* __restrict__ code,
                           float* __restrict__ qlv){
  __shared__ float red[4];
  int n = blockIdx.x;
  int l = threadIdx.x;           // 256 positions, l = ir*16+ic
  int ir = l >> 4, ic = l & 15;
  const float* cn = cosb + n * P2304;
  float cs4 = cn[(16 + ir) * 48 + (16 + ic)];
  const float wts[9] = {1.f, 2.f, 4.f, 8.f, 0.f, 16.f, 32.f, 64.f, 128.f};
  float codev = 0.f;
#pragma unroll
  for (int j = 0; j < 9; j++){
    int jr = j / 3, jc = j - 3 * (j / 3);
    float vv = cn[(jr * 16 + ir) * 48 + (jc * 16 + ic)];
    if (vv > cs4) codev += wts[j];
  }
  float w;
  w = wredMin(codev);
  if ((l & 63) == 0) red[l >> 6] = w;
  __syncthreads();
  float mn = fminf(fminf(red[0], red[1]), fminf(red[2], red[3]));
  __syncthreads();
  w = wredMax(codev);
  if ((l & 63) == 0) red[l >> 6] = w;
  __syncthreads();
  float mx = fmaxf(fmaxf(red[0], red[1]), fmaxf(red[2], red[3]));
  __syncthreads();
  float cd = (codev - mn) / (mx - mn);
  w = wredMin(cd);
  if ((l & 63) == 0) red[l >> 6] = w;
  __syncthreads();
  float cmin = fminf(fminf(red[0], red[1]), fminf(red[2], red[3]));
  __syncthreads();
  w = wredMax(cd);
  if ((l & 63) == 0) red[l >> 6] = w;
  __syncthreads();
  float cmax = fmaxf(fmaxf(red[0], red[1]), fmaxf(red[2], red[3]));
  code[n * 256 + l] = cd;
  if (l < 128){
    float tmp = (float)(2 * l + 1) * (1.0f / 256.0f);
    qlv[n * 128 + l] = tmp * (cmax - cmin) + cmin;
  }
}

__global__ void quant_kernel(const float* __restrict__ code, const float* __restrict__ qlv,
                             float* __restrict__ quantT){
  __shared__ float cs[256];
  __shared__ float qs[128];
  int n = blockIdx.x, t = threadIdx.x;
  cs[t] = code[n * 256 + t];
  if (t < 128) qs[t] = qlv[n * 128 + t];
  __syncthreads();
  float thr = 1.0f - (qs[1] - qs[0]);
  float* dst = quantT + n * LEV * 256;
#pragma unroll 4
  for (int i = 0; i < 128; i++){
    int v = t + 256 * i;
    int lv = v >> 8;
    int p = v & 255;
    float qq = 1.0f - fabsf(qs[lv] - cs[p]);
    dst[v] = (qq > thr) ? qq : 0.f;
  }
}

// sta phase A: rowsum per (n,lev), coalesced float4 reads, wave per row
__global__ void sta_rows_kernel(const float* __restrict__ quantT, float* __restrict__ raw){
  int b = blockIdx.x;                 // 1024 = 32n * 32
  int t = threadIdx.x;                // 256 = 4 waves
  int n = b >> 5;
  int row = (b & 31) * 4 + (t >> 6);  // wave -> row
  int lane = t & 63;
  const float* src = quantT + ((size_t)(n * LEV + row)) * 256 + lane * 4;
  float4 v = *(const float4*)src;
  float s = v.x + v.y + v.z + v.w;
  s = wredSum(s);
  if (lane == 0) raw[n * 128 + row] = s;
}

// sta phase B: normalize by per-n total
__global__ void sta_norm_kernel(const float* __restrict__ raw, float* __restrict__ sta){
  __shared__ float red[2];
  int n = blockIdx.x, t = threadIdx.x; // 128
  float v = raw[n * 128 + t];
  float w = wredSum(v);
  if ((t & 63) == 0) red[t >> 6] = w;
  __syncthreads();
  sta[n * 128 + t] = v / (red[0] + red[1]);
}

// h2 = relu(bn_f2(f2_w @ leaky(f1_w ⊗ [qlv; sta])))  -- h1 fused on the fly
__global__ void h2_fused_kernel(const float* __restrict__ f1w, const float* __restrict__ f2w,
                                const float* __restrict__ qlv, const float* __restrict__ sta,
                                const float* __restrict__ g, const float* __restrict__ bb,
                                const float* __restrict__ mm, const float* __restrict__ vv,
                                float* __restrict__ h2){
  int idx = blockIdx.x * 256 + threadIdx.x;   // 512 blocks: 32n x 32og x 128l
  if (idx >= N_IMG * 32 * 128) return;
  int l = idx & 127;
  int o0 = ((idx >> 7) & 31) << 2;
  int n = idx >> 12;
  float qv = qlv[n * 128 + l];
  float sv = sta[n * 128 + l];
  const float* w0 = f2w + (o0 + 0) * 64;
  const float* w1 = f2w + (o0 + 1) * 64;
  const float* w2 = f2w + (o0 + 2) * 64;
  const float* w3 = f2w + (o0 + 3) * 64;
  float a0 = 0, a1 = 0, a2 = 0, a3 = 0;
  for (int c = 0; c < 64; c++){
    float hv = f1w[2 * c] * qv + f1w[2 * c + 1] * sv;
    hv = hv > 0.f ? hv : 0.01f * hv;
    a0 += w0[c] * hv; a1 += w1[c] * hv; a2 += w2[c] * hv; a3 += w3[c] * hv;
  }
  float av[4] = {a0, a1, a2, a3};
#pragma unroll
  for (int j = 0; j < 4; j++){
    int o = o0 + j;
    float s = g[o] * (1.0f / sqrtf(vv[o] + 1e-5f));
    float val = (av[j] - mm[o]) * s + bb[o];
    h2[(n * 128 + o) * 128 + l] = fmaxf(val, 0.f);
  }
}

// s2 = relu(bn_out1(out1_w @ concat(h2, xave_bcast)))  -- concat fused
__global__ void out1_fused_kernel(const float* __restrict__ Wm, const float* __restrict__ h2,
                                  const float* __restrict__ xave,
                                  const float* __restrict__ g, const float* __restrict__ bb,
                                  const float* __restrict__ mm, const float* __restrict__ vv,
                                  float* __restrict__ s2){
  int idx = blockIdx.x * 256 + threadIdx.x;   // 1024 blocks: 32n x 64og x 128l
  if (idx >= N_IMG * 64 * 128) return;
  int l = idx & 127;
  int o0 = ((idx >> 7) & 63) << 2;
  int n = idx >> 13;
  const float* h2n = h2 + (n * 128) * 128 + l;
  const float* xa = xave + n * 128;
  const float* w0 = Wm + (o0 + 0) * 256;
  const float* w1 = Wm + (o0 + 1) * 256;
  const float* w2 = Wm + (o0 + 2) * 256;
  const float* w3 = Wm + (o0 + 3) * 256;
  float a0 = 0, a1 = 0, a2 = 0, a3 = 0;
  for (int c = 0; c < 128; c++){
    float bv = h2n[c * 128];
    a0 += w0[c] * bv; a1 += w1[c] * bv; a2 += w2[c] * bv; a3 += w3[c] * bv;
  }
  for (int c = 0; c < 128; c++){
    float bv = xa[c];
    a0 += w0[128 + c] * bv; a1 += w1[128 + c] * bv;
    a2 += w2[128 + c] * bv; a3 += w3[128 + c] * bv;
  }
  float av[4] = {a0, a1, a2, a3};
#pragma unroll
  for (int j = 0; j < 4; j++){
    int o = o0 + j;
    float s = g[o] * (1.0f / sqrtf(vv[o] + 1e-5f));
    float val = (av[j] - mm[o]) * s + bb[o];
    s2[(n * 256 + o) * 128 + l] = fmaxf(val, 0.f);
  }
}

__global__ void gemm_w_kernel(const float* __restrict__ Wm, const float* __restrict__ B,
                              float* __restrict__ Cout, int Cdim, int O, int total, int mode,
                              const float* __restrict__ g, const float* __restrict__ bb,
                              const float* __restrict__ mm, const float* __restrict__ vv){
  int idx = blockIdx.x * 256 + threadIdx.x;
  if (idx >= total) return;
  int per_n = (O >> 2) << 7;
  int n = idx / per_n;
  int rem = idx - n * per_n;
  int o0 = (rem >> 7) << 2;
  int l = rem & 127;
  const float* Bn = B + (n * Cdim) * 128 + l;
  const float* w0 = Wm + (o0 + 0) * Cdim;
  const float* w1 = Wm + (o0 + 1) * Cdim;
  const float* w2 = Wm + (o0 + 2) * Cdim;
  const float* w3 = Wm + (o0 + 3) * Cdim;
  float a0 = 0, a1 = 0, a2 = 0, a3 = 0;
  for (int c = 0; c < Cdim; c++){
    float bv = Bn[c * 128];
    a0 += w0[c] * bv; a1 += w1[c] * bv; a2 += w2[c] * bv; a3 += w3[c] * bv;
  }
  float av[4] = {a0, a1, a2, a3};
#pragma unroll
  for (int j = 0; j < 4; j++){
    int o = o0 + j;
    float val = av[j];
    if (mode == 1){
      float s = g[o] * (1.0f / sqrtf(vv[o] + 1e-5f));
      val = (val - mm[o]) * s + bb[o];
      val = fmaxf(val, 0.f);
    }
    Cout[(n * O + o) * 128 + l] = val;
  }
}

// fused k/q/v projections (one launch, shared B in L2)
__global__ void gemm_kqv_kernel(const float* __restrict__ kW, const float* __restrict__ qW,
                                const float* __restrict__ vW, const float* __restrict__ B,
                                float* __restrict__ kO, float* __restrict__ qO,
                                float* __restrict__ vO){
  int idx = blockIdx.x * 256 + threadIdx.x;   // 3 * 262144
  int sel = idx >> 18;
  int rem = idx & 262143;
  const float* Wm = (sel == 0) ? kW : (sel == 1) ? qW : vW;
  float* Cout     = (sel == 0) ? kO : (sel == 1) ? qO : vO;
  int n = rem >> 13;
  int r2 = rem & 8191;
  int o0 = (r2 >> 7) << 2;
  int l = r2 & 127;
  const float* Bn = B + (n * 256) * 128 + l;
  const float* w0 = Wm + (o0 + 0) * 256;
  const float* w1 = Wm + (o0 + 1) * 256;
  const float* w2 = Wm + (o0 + 2) * 256;
  const float* w3 = Wm + (o0 + 3) * 256;
  float a0 = 0, a1 = 0, a2 = 0, a3 = 0;
  for (int c = 0; c < 256; c++){
    float bv = Bn[c * 128];
    a0 += w0[c] * bv; a1 += w1[c] * bv; a2 += w2[c] * bv; a3 += w3[c] * bv;
  }
  float* dst = Cout + (n * 256 + o0) * 128 + l;
  dst[0] = a0; dst[128] = a1; dst[256] = a2; dst[384] = a3;
}

// attn scores + row softmax + transposed write, all in one pass.
// Block = one n, 8 l-rows, all 128 m. Row (n,l) softmax over m via
// wave-reduce + 2-wave LDS combine. Writes scT[n][m][l] directly.
__global__ void attn_scsm_kernel(const float* __restrict__ k, const float* __restrict__ q,
                                 float* __restrict__ scT){
  __shared__ float redm[2][2][4];
  __shared__ float reds[2][2][4];
  int b = blockIdx.x;                 // 512 = 32n * 16
  int t = threadIdx.x;                // 256
  int n = b >> 4;
  int h = t >> 7;                     // half: which 4 rows
  int wv = (t >> 6) & 1;              // wave within half
  int lane = t & 63;
  int m = t & 127;
  int l0 = (((b & 15) * 2 + h)) * 4;
  const float* kn = k + n * 256 * 128;
  const float* qn = q + n * 256 * 128 + m;
  float a0 = 0, a1 = 0, a2 = 0, a3 = 0;
  for (int c = 0; c < 256; c++){
    float qv = qn[c * 128];
    const float* kr = kn + c * 128 + l0;
    a0 += kr[0] * qv; a1 += kr[1] * qv; a2 += kr[2] * qv; a3 += kr[3] * qv;
  }
  float av[4] = {a0, a1, a2, a3};
#pragma unroll
  for (int r = 0; r < 4; r++){
    float w = wredMax(av[r]);
    if (lane == 0) redm[h][wv][r] = w;
  }
  __syncthreads();
  float ex[4];
#pragma unroll
  for (int r = 0; r < 4; r++){
    float mx = fmaxf(redm[h][0][r], redm[h][1][r]);
    ex[r] = expf(av[r] - mx);
    float s = wredSum(ex[r]);
    if (lane == 0) reds[h][wv][r] = s;
  }
  __syncthreads();
  float* dst = scT + n * 16384 + m * 128 + l0;
#pragma unroll
  for (int r = 0; r < 4; r++){
    dst[r] = ex[r] / (reds[h][0][r] + reds[h][1][r]);
  }
}

__global__ void attn_f_kernel(const float* __restrict__ vb, const float* __restrict__ scT,
                              float* __restrict__ f){
  int idx = blockIdx.x * 256 + threadIdx.x;
  if (idx >= N_IMG * 64 * 128) return;
  int l = idx & 127;
  int c0 = ((idx >> 7) & 63) << 2;
  int n = idx >> 13;
  const float* vn = vb + (n * 256 + c0) * 128;
  const float* sn = scT + n * 128 * 128 + l;
  float a0 = 0, a1 = 0, a2 = 0, a3 = 0;
  for (int m = 0; m < 128; m++){
    float sv = sn[m * 128];
    a0 += vn[m] * sv; a1 += vn[128 + m] * sv; a2 += vn[256 + m] * sv; a3 += vn[384 + m] * sv;
  }
  float* dst = f + (n * 256 + c0) * 128 + l;
  dst[0] = a0; dst[128] = a1; dst[256] = a2; dst[384] = a3;
}

__global__ void final_kernel(const float* __restrict__ g, const float* __restrict__ quantT,
                             float* __restrict__ outs){
  int idx = blockIdx.x * 256 + threadIdx.x;
  if (idx >= N_IMG * 64 * 256) return;
  int p = idx & 255;
  int c0 = ((idx >> 8) & 63) << 2;
  int n = idx >> 14;
  const float* gn = g + (n * 256 + c0) * 128;
  const float* qn = quantT + (n * LEV) * 256 + p;
  float a0 = 0, a1 = 0, a2 = 0, a3 = 0;
  for (int lv = 0; lv < 128; lv++){
    float qv = qn[lv * 256];
    a0 += gn[lv] * qv; a1 += gn[128 + lv] * qv; a2 += gn[256 + lv] * qv; a3 += gn[384 + lv] * qv;
  }
  float* dst = outs + (n * 256 + c0) * 256 + p;
  dst[0] = a0; dst[256] = a1; dst[512] = a2; dst[768] = a3;
}

__global__ void resize_kernel(const float* __restrict__ outs, float* __restrict__ dout){
  int idx = blockIdx.x * 256 + threadIdx.x;
  if (idx >= N_IMG * 256 * P2304) return;
  int ow = idx % 48;
  int tmp = idx / 48;
  int oh = tmp % 48;
  int nc = tmp / 48;
  const float* src = outs + nc * 256;
  float fy = oh * (15.0f / 47.0f);
  float fx = ow * (15.0f / 47.0f);
  int y0 = (int)fy;
  int x0 = (int)fx;
  int y1 = min(y0 + 1, 15);
  int x1 = min(x0 + 1, 15);
  float wy = fy - (float)y0;
  float wx = fx - (float)x0;
  float v00 = src[y0 * 16 + x0], v01 = src[y0 * 16 + x1];
  float v10 = src[y1 * 16 + x0], v11 = src[y1 * 16 + x1];
  dout[idx] = v00 * (1.f - wy) * (1.f - wx) + v01 * (1.f - wy) * wx
            + v10 * wy * (1.f - wx) + v11 * wy * wx;
}

// ---------------- launcher ----------------
extern "C" void kernel_launch(void* const* d_in, const int* in_sizes, int n_in,
                              void* d_out, int out_size, void* d_ws, size_t ws_size,
                              hipStream_t stream)
{
  const float* x       = (const float*)d_in[0];
  const float* conv1_w = (const float*)d_in[1];
  const float* bn1_g   = (const float*)d_in[2];
  const float* bn1_b   = (const float*)d_in[3];
  const float* bn1_m   = (const float*)d_in[4];
  const float* bn1_v   = (const float*)d_in[5];
  const float* conv2_w = (const float*)d_in[6];
  const float* f1_w    = (const float*)d_in[7];
  const float* f2_w    = (const float*)d_in[8];
  const float* f2_g    = (const float*)d_in[9];
  const float* f2_b    = (const float*)d_in[10];
  const float* f2_m    = (const float*)d_in[11];
  const float* f2_v    = (const float*)d_in[12];
  const float* out1_w  = (const float*)d_in[13];
  const float* out1_g  = (const float*)d_in[14];
  const float* out1_b  = (const float*)d_in[15];
  const float* out1_m  = (const float*)d_in[16];
  const float* out1_v  = (const float*)d_in[17];
  const float* k_w     = (const float*)d_in[18];
  const float* q_w     = (const float*)d_in[19];
  const float* v_w     = (const float*)d_in[20];
  const float* out_w   = (const float*)d_in[21];
  const float* out_g   = (const float*)d_in[22];
  const float* out_b   = (const float*)d_in[23];
  const float* out_m   = (const float*)d_in[24];
  const float* out_v   = (const float*)d_in[25];

  float* ws = (float*)d_ws;
  float* dout = (float*)d_out;

  // fixed region (same layout as baseline)
  float* w_y   = ws;                  // 18874368 f (fast path: yh/yl u16 pair)
  float* w_x2  = ws + 18874368;       // 9437184 f
  float* w_W1h = ws + 28311552;       // 589824
  float* w_W1l = ws + 28901376;       // 589824
  float* w_W2h = ws + 29491200;       // 16384
  float* w_W2l = ws + 29507584;       // 16384
  float* w_s1  = ws + 29523968;       // 256
  float* w_t1  = ws + 29524224;       // 256  => fixed total 29524480 f
  // small buffers reuse the y region (only written after conv2 consumed y)
  float* w_xave = w_y + 0;
  float* w_xan  = w_y + 4096;
  float* w_cos  = w_y + 8192;
  float* w_code = w_y + 81920;
  float* w_qlv  = w_y + 90112;
  float* w_sta  = w_y + 94208;
  float* w_quant= w_y + 98304;
  float* w_h2   = w_y + 1409024;
  float* w_k    = w_y + 2981888;
  float* w_q    = w_y + 4030464;
  float* w_v    = w_y + 5079040;
  float* w_scT  = w_y + 6651904;
  float* w_f    = w_y + 7176192;
  float* w_g    = w_y + 8224768;
  float* w_outs = w_y + 9273344;
  float* w_s2   = w_y + 11370496;
  float* w_raw  = w_y + 12419072;     // 4096 (sta rowsums)

  prep_w1_kernel<<<576, 256, 0, stream>>>(conv1_w, (uint4*)w_W1h, (uint4*)w_W1l);
  prep_w2_kernel<<<16, 256, 0, stream>>>(conv2_w, (uint4*)w_W2h, (uint4*)w_W2l);
  prep_bn_kernel<<<1, 256, 0, stream>>>(bn1_g, bn1_b, bn1_m, bn1_v, w_s1, w_t1);

  // --- conv1/conv2: fast path selection by available workspace ---
  const size_t BASE_F = 29524480;
  const size_t XPI_F  = 640000;                   // floats per image per array
  const size_t ws_f = ws_size / 4;
  int NCc = 0;
  if (ws_f >= BASE_F + 2 * 32 * XPI_F)      NCc = 32;
  else if (ws_f >= BASE_F + 2 * 16 * XPI_F) NCc = 16;

  if (NCc > 0){
    u16* w_xh = (u16*)(ws + BASE_F);
    u16* w_xl = w_xh + (size_t)NCc * 1280000;
    u16* w_yh = (u16*)w_y;                        // 18.87M u16 = 9437184 f
    u16* w_yl = (u16*)(w_y + 9437184);            // fills w_y region exactly
    const int nchunk = N_IMG / NCc;
    for (int c = 0; c < nchunk; ++c){
      int n0 = c * NCc;
      prep_x_kernel<<<NCc * 50, 256, 0, stream>>>(x, w_xh, w_xl, n0);
      if (NCc == 32)
        conv1_lds_kernel<32><<<1152, 256, 0, stream>>>(
            w_xh, w_xl, (const uint4*)w_W1h, (const uint4*)w_W1l, w_s1, w_t1,
            w_yh, w_yl, n0);
      else
        conv1_lds_kernel<16><<<576, 256, 0, stream>>>(
            w_xh, w_xl, (const uint4*)w_W1h, (const uint4*)w_W1l, w_s1, w_t1,
            w_yh, w_yl, n0);
    }
    conv2_lds_kernel<<<576, 256, 0, stream>>>(
        w_yh, w_yl, (const uint4*)w_W2h, (const uint4*)w_W2l, w_x2);
  } else {
    conv_mfma_kernel<9, 512, 2, true><<<1152, 256, 0, stream>>>(
        x, (const uint4*)w_W1h, (const uint4*)w_W1l, w_s1, w_t1, w_y);
    conv_mfma_kernel<1, 256, 1, false><<<576, 256, 0, stream>>>(
        w_y, (const uint4*)w_W2h, (const uint4*)w_W2l, w_s1, w_t1, w_x2);
  }

  xave_kernel<<<4096, 256, 0, stream>>>(w_x2, w_xave);
  xan_kernel<<<32, 128, 0, stream>>>(w_xave, w_xan);
  cos_kernel<<<288, 256, 0, stream>>>(w_x2, w_xan, w_cos);
  lbp_kernel<<<32, 256, 0, stream>>>(w_cos, w_code, w_qlv);
  quant_kernel<<<32, 256, 0, stream>>>(w_code, w_qlv, w_quant);
  sta_rows_kernel<<<1024, 256, 0, stream>>>(w_quant, w_raw);
  sta_norm_kernel<<<32, 128, 0, stream>>>(w_raw, w_sta);
  h2_fused_kernel<<<512, 256, 0, stream>>>(f1_w, f2_w, w_qlv, w_sta,
                                           f2_g, f2_b, f2_m, f2_v, w_h2);
  out1_fused_kernel<<<1024, 256, 0, stream>>>(out1_w, w_h2, w_xave,
                                              out1_g, out1_b, out1_m, out1_v, w_s2);
  gemm_kqv_kernel<<<3072, 256, 0, stream>>>(k_w, q_w, v_w, w_s2, w_k, w_q, w_v);
  attn_scsm_kernel<<<512, 256, 0, stream>>>(w_k, w_q, w_scT);
  attn_f_kernel<<<1024, 256, 0, stream>>>(w_v, w_scT, w_f);
  gemm_w_kernel<<<1024, 256, 0, stream>>>(out_w, w_f, w_g, 256, 256, N_IMG * 64 * 128, 1,
                                          out_g, out_b, out_m, out_v);
  final_kernel<<<2048, 256, 0, stream>>>(w_g, w_quant, w_outs);
  resize_kernel<<<73728, 256, 0, stream>>>(w_outs, dout);
}

// Round 11
// 1459.857 us; speedup vs baseline: 1.0868x; 1.0174x over previous
//
#include <hip/hip_runtime.h>
#include <math.h>

#define N_IMG 32
#define P2304 2304
#define CIN 512
#define CMID 256
#define C2 128
#define LEV 128

typedef _Float16 half8 __attribute__((ext_vector_type(8)));
typedef float f32x16 __attribute__((ext_vector_type(16)));
typedef unsigned short u16;
typedef unsigned int u32;

// ---------------- wave/block reduction helpers (wave = 64) ----------------
__device__ __forceinline__ float wredSum(float v){
#pragma unroll
  for (int o = 32; o > 0; o >>= 1) v += __shfl_down(v, o, 64);
  return v;
}
__device__ __forceinline__ float wredMax(float v){
#pragma unroll
  for (int o = 32; o > 0; o >>= 1) v = fmaxf(v, __shfl_down(v, o, 64));
  return v;
}
__device__ __forceinline__ float wredMin(float v){
#pragma unroll
  for (int o = 32; o > 0; o >>= 1) v = fminf(v, __shfl_down(v, o, 64));
  return v;
}

// async 16B global -> LDS (wave-uniform LDS base + lane*16)
__device__ __forceinline__ void gll16(const void* g, void* l){
  __builtin_amdgcn_global_load_lds(
      (const __attribute__((address_space(1))) void*)g,
      (__attribute__((address_space(3))) void*)l, 16, 0, 0);
}

// ---------------- weight prepack: split f32 -> (hi, lo*2^11) f16 frags ----
// COALESCED version: one block per co; stage the contiguous 18KB weight row
// through LDS, then emit the same fragment layout as before:
// fid = ((kt*2 + cot)*4 + c32)*64 + khalf*32 + (co&31), element j at
// k = kt*16 + khalf*8 + j, value w1[co*4608 + ci*9 + r] (r=k>>9, ci=k&511).
__global__ void prep_w1_kernel(const float* __restrict__ w1,
                               uint4* __restrict__ Wh, uint4* __restrict__ Wl){
  __shared__ float wbuf[4608];
  const int co = blockIdx.x;            // 256 blocks
  const int t = threadIdx.x;            // 256 threads
  const float* src = w1 + (size_t)co * 4608;
  for (int i = t; i < 4608; i += 256) wbuf[i] = src[i];
  __syncthreads();
  const int cot = co >> 7, c32 = (co >> 5) & 3, cl = co & 31;
  for (int fh = t; fh < 576; fh += 256){
    int kt = fh >> 1, khalf = fh & 1;
    half8 vh, vl;
#pragma unroll
    for (int j = 0; j < 8; ++j){
      int k = kt * 16 + khalf * 8 + j;
      int r = k >> 9, ci = k & 511;
      float v = wbuf[ci * 9 + r];
      _Float16 h = (_Float16)v;
      vh[j] = h;
      vl[j] = (_Float16)((v - (float)h) * 2048.0f);
    }
    int fid = ((kt * 2 + cot) * 4 + c32) * 64 + khalf * 32 + cl;
    Wh[fid] = *(uint4*)&vh;
    Wl[fid] = *(uint4*)&vl;
  }
}

__global__ void prep_w2_kernel(const float* __restrict__ w2,
                               uint4* __restrict__ Wh, uint4* __restrict__ Wl){
  int fid = blockIdx.x * 256 + threadIdx.x;     // 4096 frags
  int lam = fid & 63;
  int c32 = (fid >> 6) & 3;
  int kt  = fid >> 8;                           // 0..15
  int co = c32 * 32 + (lam & 31);
  half8 vh, vl;
#pragma unroll
  for (int j = 0; j < 8; ++j){
    int k = kt * 16 + ((lam >> 5) << 3) + j;    // 0..255
    float v = w2[co * CMID + k];
    _Float16 h = (_Float16)v;
    vh[j] = h;
    vl[j] = (_Float16)((v - (float)h) * 2048.0f);
  }
  Wh[fid] = *(uint4*)&vh;
  Wl[fid] = *(uint4*)&vl;
}

// s1 = g/sqrt(v+eps), t1 = b - m*s1  (bn folded to y*s1 + t1)
__global__ void prep_bn_kernel(const float* __restrict__ g1, const float* __restrict__ b1,
                               const float* __restrict__ m1, const float* __restrict__ v1,
                               float* __restrict__ s1, float* __restrict__ t1){
  int c = threadIdx.x;  // 256
  float s = g1[c] * (1.0f / sqrtf(v1[c] + 1e-5f));
  s1[c] = s;
  t1[c] = b1[c] - m1[c] * s;
}

// ---------------- FAST PATH: transpose+pad+split x (ck-chunked layout) ----
__global__ void prep_x_kernel(const float* __restrict__ x,
                              u16* __restrict__ xh, u16* __restrict__ xl,
                              int n0){
  __shared__ float tile[128 * 49];
  const int t = threadIdx.x;
  const int b = blockIdx.x;
  const int n_loc = b / 50;
  const int hp = b - n_loc * 50;
  const int n = n0 + n_loc;
  const int h = hp - 1;
  const bool vrow = (h >= 0) && (h < 48);
  const size_t base_n = (size_t)n_loc * 1280000;   // 32*2500*16 u16 per image
  for (int cc = 0; cc < 4; ++cc){                  // channels cc*128..+128
    if (vrow){
      const float* src = x + (((size_t)n * 512 + cc * 128) * 48 + h) * 48;
#pragma unroll
      for (int i = 0; i < 24; ++i){
        int idx = t + 256 * i;            // 6144 = 128c x 48w
        int w = idx % 48;
        int c = idx / 48;
        tile[c * 49 + w] = src[(size_t)c * 2304 + w];
      }
    }
    __syncthreads();
    for (int i = 0; i < 13; ++i){
      int idx = t + 256 * i;
      if (idx < 3200){
        int ck_loc = idx / 400;           // 0..7
        int rem = idx - ck_loc * 400;
        int wp = rem >> 3;                // 0..49
        int clp = rem & 7;                // channel pair within 16
        int w = wp - 1;
        int c_loc = ck_loc * 16 + clp * 2;
        float v0 = 0.f, v1 = 0.f;
        if (vrow && (unsigned)w < 48u){
          v0 = tile[c_loc * 49 + w];
          v1 = tile[(c_loc + 1) * 49 + w];
        }
        _Float16 h0 = (_Float16)v0, h1 = (_Float16)v1;
        _Float16 l0 = (_Float16)((v0 - (float)h0) * 2048.0f);
        _Float16 l1 = (_Float16)((v1 - (float)h1) * 2048.0f);
        union { _Float16 hh[2]; u32 uu; } ph, pl;
        ph.hh[0] = h0; ph.hh[1] = h1;
        pl.hh[0] = l0; pl.hh[1] = l1;
        size_t off = base_n + ((size_t)(cc * 8 + ck_loc) * 2500
                               + hp * 50 + wp) * 16 + clp * 2;  // u16 idx
        *(u32*)(xh + off) = ph.uu;
        *(u32*)(xl + off) = pl.uu;
      }
    }
    __syncthreads();
  }
}

// ---------------- shared MFMA compute macro (BK=32 lds conv kernels) ------
#define COMPUTE_M(CUR, KF)                                                    \
  {                                                                           \
    const int ct0 = (g & 1) * 2, pt0 = (g >> 1) * 2;                          \
    half8 fAh[2], fAl[2], fBh[2], fBl[2];                                     \
    _Pragma("unroll")                                                         \
    for (int a = 0; a < 2; ++a){                                              \
      fAh[a] = *(half8*)&Abuf[CUR][KF][0][(ct0 + a) * 512 + lam * 8];         \
      fAl[a] = *(half8*)&Abuf[CUR][KF][1][(ct0 + a) * 512 + lam * 8];         \
      fBh[a] = *(half8*)&Bbuf[CUR][KF][0][(pt0 + a) * 512 + lam * 8];         \
      fBl[a] = *(half8*)&Bbuf[CUR][KF][1][(pt0 + a) * 512 + lam * 8];         \
    }                                                                         \
    _Pragma("unroll")                                                         \
    for (int a = 0; a < 2; ++a)                                               \
      _Pragma("unroll")                                                       \
      for (int b = 0; b < 2; ++b){                                            \
        acc_hh[a][b] = __builtin_amdgcn_mfma_f32_32x32x16_f16(                \
            fAh[a], fBh[b], acc_hh[a][b], 0, 0, 0);                           \
        acc_x[a][b] = __builtin_amdgcn_mfma_f32_32x32x16_f16(                 \
            fAh[a], fBl[b], acc_x[a][b], 0, 0, 0);                            \
        acc_x[a][b] = __builtin_amdgcn_mfma_f32_32x32x16_f16(                 \
            fAl[a], fBh[b], acc_x[a][b], 0, 0, 0);                            \
      }                                                                       \
  }

#define WAITV8  asm volatile("s_waitcnt vmcnt(8)"  ::: "memory")
#define WAITV0  asm volatile("s_waitcnt vmcnt(0)"  ::: "memory")
#define BARSB { __builtin_amdgcn_s_barrier(); __builtin_amdgcn_sched_barrier(0); }

// ---------------- FAST conv1: 3x3 SAME, BK=32, 2-buffer counted vmcnt -----
// (r8 configuration, best measured: conv1 = 667 us)
template<int NC>
__global__ __launch_bounds__(256, 2) void conv1_lds_kernel(
    const u16* __restrict__ xh, const u16* __restrict__ xl,
    const uint4* __restrict__ Wh, const uint4* __restrict__ Wl,
    const float* __restrict__ s1, const float* __restrict__ t1,
    u16* __restrict__ yh, u16* __restrict__ yl, int n0)
{
  __shared__ _Float16 Abuf[2][2][2][2048];
  __shared__ _Float16 Bbuf[2][2][2][2048];
  const int t = threadIdx.x;
  const int lam = t & 63;
  const int g = t >> 6;                 // wave id = staged c32 (A) / p32 (B) group

  const int xcd = blockIdx.x & 7;
  const int rest = blockIdx.x >> 3;
  const int NPX = NC / 8;
  const int n_loc = xcd * NPX + rest / 36;
  const int inner = rest % 36;
  const int pt_blk = inner % 18;
  const int cot = inner / 18;
  const int n = n0 + n_loc;

  const int pbase = pt_blk * 128;
  const int khi = lam >> 5;
  const int pp = (g << 5) + (lam & 31);
  const int p = pbase + pp;
  const int ph = p / 48, pw = p - ph * 48;
  const u16* xh_n = xh + (size_t)n_loc * 1280000;
  const u16* xl_n = xl + (size_t)n_loc * 1280000;

  const int S = 144;                    // 9*512/32 BK=32 stages

  f32x16 acc_hh[2][2], acc_x[2][2];
#pragma unroll
  for (int a = 0; a < 2; ++a)
#pragma unroll
    for (int b = 0; b < 2; ++b){
#pragma unroll
      for (int e = 0; e < 16; ++e){ acc_hh[a][b][e] = 0.f; acc_x[a][b][e] = 0.f; }
    }

#define ISSUE1(SV, BUF)                                                       \
  {                                                                           \
    int s_ = (SV);                                                            \
    int k0_ = 2 * s_;                                                         \
    _Pragma("unroll")                                                         \
    for (int kf = 0; kf < 2; ++kf){                                           \
      int fg_ = ((k0_ + kf) * 2 + cot) * 4 + g;                               \
      gll16(Wh + fg_ * 64 + lam, &Abuf[BUF][kf][0][t * 8]);                   \
      gll16(Wl + fg_ * 64 + lam, &Abuf[BUF][kf][1][t * 8]);                   \
    }                                                                         \
    int r_ = k0_ >> 5;                  /* tap 0..8 */                        \
    int ck0_ = k0_ & 31;                /* 16-ch chunk base (even) */         \
    int qpp_ = (ph + r_ / 3) * 50 + (pw + r_ % 3);   /* padded pos */         \
    _Pragma("unroll")                                                         \
    for (int kf = 0; kf < 2; ++kf){                                           \
      size_t o_ = ((size_t)(ck0_ + kf) * 2500 + qpp_) * 16 + (khi << 3);      \
      gll16(xh_n + o_, &Bbuf[BUF][kf][0][t * 8]);                             \
      gll16(xl_n + o_, &Bbuf[BUF][kf][1][t * 8]);                             \
    }                                                                         \
  }

  ISSUE1(0, 0);
  ISSUE1(1, 1);

  for (int s = 0; s < S - 1; ++s){
    WAITV8;
    BARSB;
    __builtin_amdgcn_s_setprio(1);
    COMPUTE_M(s & 1, 0);
    COMPUTE_M(s & 1, 1);
    __builtin_amdgcn_s_setprio(0);
    if (s + 2 < S){
      BARSB;
      ISSUE1(s + 2, s & 1);
    }
  }
  WAITV0;
  BARSB;
  __builtin_amdgcn_s_setprio(1);
  COMPUTE_M((S - 1) & 1, 0);
  COMPUTE_M((S - 1) & 1, 1);
  __builtin_amdgcn_s_setprio(0);
#undef ISSUE1

  // epilogue: combine hi/lo, bn+leaky, split f16, store y [n][co16][p][16]
  const int cobase = cot * 128;
#pragma unroll
  for (int a = 0; a < 2; ++a){
    const int ctile = (g & 1) * 2 + a;
#pragma unroll
    for (int b = 0; b < 2; ++b){
      const int ptile = (g >> 1) * 2 + b;
      const int pg = pbase + ptile * 32 + (lam & 31);
#pragma unroll
      for (int q = 0; q < 4; ++q){
        const int co0 = cobase + ctile * 32 + 8 * q + 4 * khi;
        const int co16 = co0 >> 4, col = co0 & 15;
        union { _Float16 h[4]; uint2 u; } Uh, Ul;
#pragma unroll
        for (int i = 0; i < 4; ++i){
          const int rg = 4 * q + i;
          const int co = co0 + i;
          float val = acc_hh[a][b][rg] + acc_x[a][b][rg] * (1.0f / 2048.0f);
          val = val * s1[co] + t1[co];
          val = val > 0.f ? val : 0.01f * val;
          _Float16 h = (_Float16)val;
          Uh.h[i] = h;
          Ul.h[i] = (_Float16)((val - (float)h) * 2048.0f);
        }
        size_t off = (((size_t)n * 16 + co16) * P2304 + pg) * 16 + col;
        *(uint2*)(yh + off) = Uh.u;
        *(uint2*)(yl + off) = Ul.u;
      }
    }
  }
}

// ---------------- FAST conv2: 1x1 over [co16][p][16] split-f16 y ----------
__global__ __launch_bounds__(256, 2) void conv2_lds_kernel(
    const u16* __restrict__ yh, const u16* __restrict__ yl,
    const uint4* __restrict__ Wh, const uint4* __restrict__ Wl,
    float* __restrict__ out)
{
  __shared__ _Float16 Abuf[2][2][2][2048];
  __shared__ _Float16 Bbuf[2][2][2][2048];
  const int t = threadIdx.x;
  const int lam = t & 63;
  const int g = t >> 6;

  const int pt_blk = blockIdx.x % 18;
  const int n = blockIdx.x / 18;
  const int pbase = pt_blk * 128;
  const int khi = lam >> 5;
  const int p = pbase + (g << 5) + (lam & 31);
  const u16* yh_n = yh + (size_t)n * 589824;     // 16*2304*16
  const u16* yl_n = yl + (size_t)n * 589824;

  const int S = 8;

  f32x16 acc_hh[2][2], acc_x[2][2];
#pragma unroll
  for (int a = 0; a < 2; ++a)
#pragma unroll
    for (int b = 0; b < 2; ++b){
#pragma unroll
      for (int e = 0; e < 16; ++e){ acc_hh[a][b][e] = 0.f; acc_x[a][b][e] = 0.f; }
    }

#define ISSUE2(SV, BUF)                                                       \
  {                                                                           \
    int s_ = (SV);                                                            \
    int k0_ = 2 * s_;                                                         \
    _Pragma("unroll")                                                         \
    for (int kf = 0; kf < 2; ++kf){                                           \
      int fg_ = (k0_ + kf) * 4 + g;                                           \
      gll16(Wh + fg_ * 64 + lam, &Abuf[BUF][kf][0][t * 8]);                   \
      gll16(Wl + fg_ * 64 + lam, &Abuf[BUF][kf][1][t * 8]);                   \
    }                                                                         \
    _Pragma("unroll")                                                         \
    for (int kf = 0; kf < 2; ++kf){                                           \
      size_t o_ = ((size_t)(k0_ + kf) * P2304 + p) * 16 + (khi << 3);         \
      gll16(yh_n + o_, &Bbuf[BUF][kf][0][t * 8]);                             \
      gll16(yl_n + o_, &Bbuf[BUF][kf][1][t * 8]);                             \
    }                                                                         \
  }

  ISSUE2(0, 0);
  ISSUE2(1, 1);

  for (int s = 0; s < S - 1; ++s){
    WAITV8;
    BARSB;
    __builtin_amdgcn_s_setprio(1);
    COMPUTE_M(s & 1, 0);
    COMPUTE_M(s & 1, 1);
    __builtin_amdgcn_s_setprio(0);
    if (s + 2 < S){
      BARSB;
      ISSUE2(s + 2, s & 1);
    }
  }
  WAITV0;
  BARSB;
  __builtin_amdgcn_s_setprio(1);
  COMPUTE_M((S - 1) & 1, 0);
  COMPUTE_M((S - 1) & 1, 1);
  __builtin_amdgcn_s_setprio(0);
#undef ISSUE2

  // epilogue: combine hi/lo, store x2 f32 [n][co][p]
#pragma unroll
  for (int a = 0; a < 2; ++a){
    const int ctile = (g & 1) * 2 + a;
#pragma unroll
    for (int b = 0; b < 2; ++b){
      const int ptile = (g >> 1) * 2 + b;
      const int pg = pbase + ptile * 32 + (lam & 31);
#pragma unroll
      for (int rg = 0; rg < 16; ++rg){
        const int row = (rg & 3) + 8 * (rg >> 2) + 4 * khi;
        const int co = ctile * 32 + row;
        float val = acc_hh[a][b][rg] + acc_x[a][b][rg] * (1.0f / 2048.0f);
        out[((size_t)n * C2 + co) * P2304 + pg] = val;
      }
    }
  }
}

// ---------------- FALLBACK split-f16 MFMA conv (3x3 SAME or 1x1) ----------
template<int R, int CPT, int COTN, bool BN>
__global__ __launch_bounds__(256, 2) void conv_mfma_kernel(
    const float* __restrict__ in, const uint4* __restrict__ Wh, const uint4* __restrict__ Wl,
    const float* __restrict__ s1, const float* __restrict__ t1, float* __restrict__ out)
{
  __shared__ _Float16 Abuf[2][2][2][2048];
  __shared__ _Float16 Bbuf[2][2][2][2048];
  const int t = threadIdx.x;
  const int lam = t & 63;
  const int g = t >> 6;

  int n, pt_blk, cot;
  if (COTN == 2){
    int xcd = blockIdx.x & 7;
    int rest = blockIdx.x >> 3;
    n = xcd * 4 + rest / 36;
    int inner = rest % 36;
    pt_blk = inner % 18;
    cot = inner / 18;
  } else {
    pt_blk = blockIdx.x % 18;
    cot = 0;
    n = blockIdx.x / 18;
  }
  const int pbase = pt_blk * 128;
  const int cobase = cot * 128;

  const int khi = lam >> 5;
  const int pp = (g << 5) + (lam & 31);
  const int p = pbase + pp;
  const int ph = p / 48, pw = p - ph * 48;
  const float* in_n = in + (size_t)n * CPT * P2304;

  const int S = (R * CPT) / 32;
  const int KTPT = CPT / 16;

  f32x16 acc_hh[2][2], acc_x[2][2];
#pragma unroll
  for (int a = 0; a < 2; ++a)
#pragma unroll
    for (int b = 0; b < 2; ++b){
#pragma unroll
      for (int e = 0; e < 16; ++e){ acc_hh[a][b][e] = 0.f; acc_x[a][b][e] = 0.f; }
    }

  uint4 rAh[2], rAl[2];
  float rB[16];
  bool vmask;

#define ISSUE(SV)                                                             \
  {                                                                           \
    int s_ = (SV);                                                            \
    _Pragma("unroll")                                                         \
    for (int kf = 0; kf < 2; ++kf){                                           \
      int fi = (((2 * s_ + kf) * COTN + cot) * 4 + g) * 64 + lam;             \
      rAh[kf] = Wh[fi];                                                       \
      rAl[kf] = Wl[fi];                                                       \
    }                                                                         \
    int r_ = (R == 1) ? 0 : ((2 * s_) / KTPT);                                \
    int cbase_ = ((2 * s_) % KTPT) * 16;                                      \
    int dh_ = (R == 1) ? 0 : (r_ / 3 - 1);                                    \
    int dw_ = (R == 1) ? 0 : (r_ - (r_ / 3) * 3 - 1);                         \
    int hh_ = ph + dh_, ww_ = pw + dw_;                                       \
    vmask = ((unsigned)hh_ < 48u) & ((unsigned)ww_ < 48u);                    \
    int hc_ = min(max(hh_, 0), 47), wc_ = min(max(ww_, 0), 47);               \
    const float* src_ = in_n + hc_ * 48 + wc_                                 \
                        + (size_t)(cbase_ + khi * 8) * P2304;                 \
    _Pragma("unroll")                                                         \
    for (int kf = 0; kf < 2; ++kf)                                            \
      _Pragma("unroll")                                                       \
      for (int j = 0; j < 8; ++j)                                             \
        rB[kf * 8 + j] = src_[(kf * 16 + j) * P2304];                         \
  }

#define STASH(NXT)                                                            \
  {                                                                           \
    _Pragma("unroll")                                                         \
    for (int kf = 0; kf < 2; ++kf){                                           \
      *(uint4*)&Abuf[NXT][kf][0][t * 8] = rAh[kf];                            \
      *(uint4*)&Abuf[NXT][kf][1][t * 8] = rAl[kf];                            \
      half8 vh, vl;                                                           \
      _Pragma("unroll")                                                       \
      for (int j = 0; j < 8; ++j){                                            \
        float v = vmask ? rB[kf * 8 + j] : 0.0f;                              \
        _Float16 h = (_Float16)v;                                             \
        vh[j] = h;                                                            \
        vl[j] = (_Float16)((v - (float)h) * 2048.0f);                         \
      }                                                                       \
      *(half8*)&Bbuf[NXT][kf][0][t * 8] = vh;                                 \
      *(half8*)&Bbuf[NXT][kf][1][t * 8] = vl;                                 \
    }                                                                         \
  }

  ISSUE(0);
  STASH(0);
  __syncthreads();

  for (int s = 0; s < S; ++s){
    const int cur = s & 1, nxt = cur ^ 1;
    const bool more = (s + 1 < S);
    if (more) ISSUE(s + 1);
    COMPUTE_M(cur, 0);
    if (more) STASH(nxt);
    COMPUTE_M(cur, 1);
    __syncthreads();
  }
#undef ISSUE
#undef STASH

  const int M = COTN * 128;
#pragma unroll
  for (int a = 0; a < 2; ++a){
    const int ctile = (g & 1) * 2 + a;
#pragma unroll
    for (int b = 0; b < 2; ++b){
      const int ptile = (g >> 1) * 2 + b;
      const int pg = pbase + ptile * 32 + (lam & 31);
#pragma unroll
      for (int rg = 0; rg < 16; ++rg){
        const int row = (rg & 3) + 8 * (rg >> 2) + 4 * (lam >> 5);
        const int co = cobase + ctile * 32 + row;
        float val = acc_hh[a][b][rg] + acc_x[a][b][rg] * (1.0f / 2048.0f);
        if (BN){
          val = val * s1[co] + t1[co];
          val = val > 0.f ? val : 0.01f * val;
        }
        out[((size_t)n * M + co) * P2304 + pg] = val;
      }
    }
  }
}

// ---------------- x_ave (mean over 2304 positions per (n,c)) ----------------
__global__ void xave_kernel(const float* __restrict__ x2, float* __restrict__ xave){
  __shared__ float red[4];
  int nc = blockIdx.x, t = threadIdx.x;
  const float* row = x2 + nc * P2304;
  float s = 0.f;
#pragma unroll
  for (int i = 0; i < 9; i++) s += row[t + 256 * i];
  float w = wredSum(s);
  if ((t & 63) == 0) red[t >> 6] = w;
  __syncthreads();
  if (t == 0) xave[nc] = (red[0] + red[1] + red[2] + red[3]) * (1.0f / 2304.0f);
}

__global__ void xan_kernel(const float* __restrict__ xave, float* __restrict__ xan){
  __shared__ float red[2];
  int n = blockIdx.x, t = threadIdx.x; // 128 threads
  float v = xave[n * 128 + t];
  float w = wredSum(v * v);
  if ((t & 63) == 0) red[t >> 6] = w;
  __syncthreads();
  float norm = fmaxf(sqrtf(red[0] + red[1]), 1e-12f);
  xan[n * 128 + t] = v / norm;
}

__global__ void cos_kernel(const float* __restrict__ x2, const float* __restrict__ xan,
                           float* __restrict__ cosb){
  int idx = blockIdx.x * 256 + threadIdx.x;
  if (idx >= N_IMG * P2304) return;
  int n = idx / P2304;
  int p = idx - n * P2304;
  const float* xp = x2 + n * C2 * P2304 + p;
  const float* an = xan + n * 128;
  float dot = 0.f, ss = 0.f;
  for (int c = 0; c < 128; c++){
    float v = xp[c * P2304];
    dot += an[c] * v;
    ss  += v * v;
  }
  cosb[idx] = dot / fmaxf(sqrtf(ss), 1e-12f);
}

// ---------------- fused LBP code + qlv + quant + sta (one block per n) ----
// Thread t owns position column p=t. Produces qlv (global), quantT, sta.
__global__ void lbp_quant_sta_kernel(const float* __restrict__ cosb,
                                     float* __restrict__ qlv,
                                     float* __restrict__ quantT,
                                     float* __restrict__ sta){
  __shared__ float red[4];
  __shared__ float cs[256];
  __shared__ float qs[128];
  __shared__ float rsw[4][128];
  int n = blockIdx.x;
  int l = threadIdx.x;           // 256 positions, l = ir*16+ic
  int ir = l >> 4, ic = l & 15;
  int wv = l >> 6, lane = l & 63;
  const float* cn = cosb + n * P2304;
  float cs4 = cn[(16 + ir) * 48 + (16 + ic)];
  const float wts[9] = {1.f, 2.f, 4.f, 8.f, 0.f, 16.f, 32.f, 64.f, 128.f};
  float codev = 0.f;
#pragma unroll
  for (int j = 0; j < 9; j++){
    int jr = j / 3, jc = j - 3 * (j / 3);
    float vv = cn[(jr * 16 + ir) * 48 + (jc * 16 + ic)];
    if (vv > cs4) codev += wts[j];
  }
  float w;
  w = wredMin(codev);
  if (lane == 0) red[wv] = w;
  __syncthreads();
  float mn = fminf(fminf(red[0], red[1]), fminf(red[2], red[3]));
  __syncthreads();
  w = wredMax(codev);
  if (lane == 0) red[wv] = w;
  __syncthreads();
  float mx = fmaxf(fmaxf(red[0], red[1]), fmaxf(red[2], red[3]));
  __syncthreads();
  float cd = (codev - mn) / (mx - mn);
  w = wredMin(cd);
  if (lane == 0) red[wv] = w;
  __syncthreads();
  float cmin = fminf(fminf(red[0], red[1]), fminf(red[2], red[3]));
  __syncthreads();
  w = wredMax(cd);
  if (lane == 0) red[wv] = w;
  __syncthreads();
  float cmax = fmaxf(fmaxf(red[0], red[1]), fmaxf(red[2], red[3]));
  cs[l] = cd;
  if (l < 128){
    float tmp = (float)(2 * l + 1) * (1.0f / 256.0f);
    float qv = tmp * (cmax - cmin) + cmin;
    qs[l] = qv;
    qlv[n * 128 + l] = qv;
  }
  __syncthreads();
  float thr = 1.0f - (qs[1] - qs[0]);
  float myc = cs[l];
  float* dst = quantT + n * LEV * 256;
  // lv = i, p = l; write coalesced; accumulate per-wave row partials
  for (int i = 0; i < 128; i++){
    float qq = 1.0f - fabsf(qs[i] - myc);
    qq = (qq > thr) ? qq : 0.f;
    dst[i * 256 + l] = qq;
    float s = wredSum(qq);
    if (lane == 0) rsw[wv][i] = s;
  }
  __syncthreads();
  if (l < 128){
    float rowsum = rsw[0][l] + rsw[1][l] + rsw[2][l] + rsw[3][l];
    // total = sum of all rowsums (over 128 levels) via 2-wave reduce
    float tt = wredSum(rowsum);
    if ((l & 63) == 0) red[l >> 6] = tt;
    __syncthreads();
    float total = red[0] + red[1];
    sta[n * 128 + l] = rowsum / total;
  }
}

// h2 = relu(bn_f2(f2_w @ leaky(f1_w ⊗ [qlv; sta])))  -- h1 fused on the fly
__global__ void h2_fused_kernel(const float* __restrict__ f1w, const float* __restrict__ f2w,
                                const float* __restrict__ qlv, const float* __restrict__ sta,
                                const float* __restrict__ g, const float* __restrict__ bb,
                                const float* __restrict__ mm, const float* __restrict__ vv,
                                float* __restrict__ h2){
  int idx = blockIdx.x * 256 + threadIdx.x;   // 512 blocks: 32n x 32og x 128l
  if (idx >= N_IMG * 32 * 128) return;
  int l = idx & 127;
  int o0 = ((idx >> 7) & 31) << 2;
  int n = idx >> 12;
  float qv = qlv[n * 128 + l];
  float sv = sta[n * 128 + l];
  const float* w0 = f2w + (o0 + 0) * 64;
  const float* w1 = f2w + (o0 + 1) * 64;
  const float* w2 = f2w + (o0 + 2) * 64;
  const float* w3 = f2w + (o0 + 3) * 64;
  float a0 = 0, a1 = 0, a2 = 0, a3 = 0;
  for (int c = 0; c < 64; c++){
    float hv = f1w[2 * c] * qv + f1w[2 * c + 1] * sv;
    hv = hv > 0.f ? hv : 0.01f * hv;
    a0 += w0[c] * hv; a1 += w1[c] * hv; a2 += w2[c] * hv; a3 += w3[c] * hv;
  }
  float av[4] = {a0, a1, a2, a3};
#pragma unroll
  for (int j = 0; j < 4; j++){
    int o = o0 + j;
    float s = g[o] * (1.0f / sqrtf(vv[o] + 1e-5f));
    float val = (av[j] - mm[o]) * s + bb[o];
    h2[(n * 128 + o) * 128 + l] = fmaxf(val, 0.f);
  }
}

// s2 = relu(bn_out1(out1_w @ concat(h2, xave_bcast)))  -- concat fused
__global__ void out1_fused_kernel(const float* __restrict__ Wm, const float* __restrict__ h2,
                                  const float* __restrict__ xave,
                                  const float* __restrict__ g, const float* __restrict__ bb,
                                  const float* __restrict__ mm, const float* __restrict__ vv,
                                  float* __restrict__ s2){
  int idx = blockIdx.x * 256 + threadIdx.x;   // 1024 blocks: 32n x 64og x 128l
  if (idx >= N_IMG * 64 * 128) return;
  int l = idx & 127;
  int o0 = ((idx >> 7) & 63) << 2;
  int n = idx >> 13;
  const float* h2n = h2 + (n * 128) * 128 + l;
  const float* xa = xave + n * 128;
  const float* w0 = Wm + (o0 + 0) * 256;
  const float* w1 = Wm + (o0 + 1) * 256;
  const float* w2 = Wm + (o0 + 2) * 256;
  const float* w3 = Wm + (o0 + 3) * 256;
  float a0 = 0, a1 = 0, a2 = 0, a3 = 0;
  for (int c = 0; c < 128; c++){
    float bv = h2n[c * 128];
    a0 += w0[c] * bv; a1 += w1[c] * bv; a2 += w2[c] * bv; a3 += w3[c] * bv;
  }
  for (int c = 0; c < 128; c++){
    float bv = xa[c];
    a0 += w0[128 + c] * bv; a1 += w1[128 + c] * bv;
    a2 += w2[128 + c] * bv; a3 += w3[128 + c] * bv;
  }
  float av[4] = {a0, a1, a2, a3};
#pragma unroll
  for (int j = 0; j < 4; j++){
    int o = o0 + j;
    float s = g[o] * (1.0f / sqrtf(vv[o] + 1e-5f));
    float val = (av[j] - mm[o]) * s + bb[o];
    s2[(n * 256 + o) * 128 + l] = fmaxf(val, 0.f);
  }
}

__global__ void gemm_w_kernel(const float* __restrict__ Wm, const float* __restrict__ B,
                              float* __restrict__ Cout, int Cdim, int O, int total, int mode,
                              const float* __restrict__ g, const float* __restrict__ bb,
                              const float* __restrict__ mm, const float* __restrict__ vv){
  int idx = blockIdx.x * 256 + threadIdx.x;
  if (idx >= total) return;
  int per_n = (O >> 2) << 7;
  int n = idx / per_n;
  int rem = idx - n * per_n;
  int o0 = (rem >> 7) << 2;
  int l = rem & 127;
  const float* Bn = B + (n * Cdim) * 128 + l;
  const float* w0 = Wm + (o0 + 0) * Cdim;
  const float* w1 = Wm + (o0 + 1) * Cdim;
  const float* w2 = Wm + (o0 + 2) * Cdim;
  const float* w3 = Wm + (o0 + 3) * Cdim;
  float a0 = 0, a1 = 0, a2 = 0, a3 = 0;
  for (int c = 0; c < Cdim; c++){
    float bv = Bn[c * 128];
    a0 += w0[c] * bv; a1 += w1[c] * bv; a2 += w2[c] * bv; a3 += w3[c] * bv;
  }
  float av[4] = {a0, a1, a2, a3};
#pragma unroll
  for (int j = 0; j < 4; j++){
    int o = o0 + j;
    float val = av[j];
    if (mode == 1){
      float s = g[o] * (1.0f / sqrtf(vv[o] + 1e-5f));
      val = (val - mm[o]) * s + bb[o];
      val = fmaxf(val, 0.f);
    }
    Cout[(n * O + o) * 128 + l] = val;
  }
}

// fused k/q/v projections (one launch, shared B in L2)
__global__ void gemm_kqv_kernel(const float* __restrict__ kW, const float* __restrict__ qW,
                                const float* __restrict__ vW, const float* __restrict__ B,
                                float* __restrict__ kO, float* __restrict__ qO,
                                float* __restrict__ vO){
  int idx = blockIdx.x * 256 + threadIdx.x;   // 3 * 262144
  int sel = idx >> 18;
  int rem = idx & 262143;
  const float* Wm = (sel == 0) ? kW : (sel == 1) ? qW : vW;
  float* Cout     = (sel == 0) ? kO : (sel == 1) ? qO : vO;
  int n = rem >> 13;
  int r2 = rem & 8191;
  int o0 = (r2 >> 7) << 2;
  int l = r2 & 127;
  const float* Bn = B + (n * 256) * 128 + l;
  const float* w0 = Wm + (o0 + 0) * 256;
  const float* w1 = Wm + (o0 + 1) * 256;
  const float* w2 = Wm + (o0 + 2) * 256;
  const float* w3 = Wm + (o0 + 3) * 256;
  float a0 = 0, a1 = 0, a2 = 0, a3 = 0;
  for (int c = 0; c < 256; c++){
    float bv = Bn[c * 128];
    a0 += w0[c] * bv; a1 += w1[c] * bv; a2 += w2[c] * bv; a3 += w3[c] * bv;
  }
  float* dst = Cout + (n * 256 + o0) * 128 + l;
  dst[0] = a0; dst[128] = a1; dst[256] = a2; dst[384] = a3;
}

// attn scores + row softmax + transposed write, all in one pass.
__global__ void attn_scsm_kernel(const float* __restrict__ k, const float* __restrict__ q,
                                 float* __restrict__ scT){
  __shared__ float redm[2][2][4];
  __shared__ float reds[2][2][4];
  int b = blockIdx.x;                 // 512 = 32n * 16
  int t = threadIdx.x;                // 256
  int n = b >> 4;
  int h = t >> 7;                     // half: which 4 rows
  int wv = (t >> 6) & 1;              // wave within half
  int lane = t & 63;
  int m = t & 127;
  int l0 = (((b & 15) * 2 + h)) * 4;
  const float* kn = k + n * 256 * 128;
  const float* qn = q + n * 256 * 128 + m;
  float a0 = 0, a1 = 0, a2 = 0, a3 = 0;
  for (int c = 0; c < 256; c++){
    float qv = qn[c * 128];
    const float* kr = kn + c * 128 + l0;
    a0 += kr[0] * qv; a1 += kr[1] * qv; a2 += kr[2] * qv; a3 += kr[3] * qv;
  }
  float av[4] = {a0, a1, a2, a3};
#pragma unroll
  for (int r = 0; r < 4; r++){
    float w = wredMax(av[r]);
    if (lane == 0) redm[h][wv][r] = w;
  }
  __syncthreads();
  float ex[4];
#pragma unroll
  for (int r = 0; r < 4; r++){
    float mx = fmaxf(redm[h][0][r], redm[h][1][r]);
    ex[r] = expf(av[r] - mx);
    float s = wredSum(ex[r]);
    if (lane == 0) reds[h][wv][r] = s;
  }
  __syncthreads();
  float* dst = scT + n * 16384 + m * 128 + l0;
#pragma unroll
  for (int r = 0; r < 4; r++){
    dst[r] = ex[r] / (reds[h][0][r] + reds[h][1][r]);
  }
}

__global__ void attn_f_kernel(const float* __restrict__ vb, const float* __restrict__ scT,
                              float* __restrict__ f){
  int idx = blockIdx.x * 256 + threadIdx.x;
  if (idx >= N_IMG * 64 * 128) return;
  int l = idx & 127;
  int c0 = ((idx >> 7) & 63) << 2;
  int n = idx >> 13;
  const float* vn = vb + (n * 256 + c0) * 128;
  const float* sn = scT + n * 128 * 128 + l;
  float a0 = 0, a1 = 0, a2 = 0, a3 = 0;
  for (int m = 0; m < 128; m++){
    float sv = sn[m * 128];
    a0 += vn[m] * sv; a1 += vn[128 + m] * sv; a2 += vn[256 + m] * sv; a3 += vn[384 + m] * sv;
  }
  float* dst = f + (n * 256 + c0) * 128 + l;
  dst[0] = a0; dst[128] = a1; dst[256] = a2; dst[384] = a3;
}

__global__ void final_kernel(const float* __restrict__ g, const float* __restrict__ quantT,
                             float* __restrict__ outs){
  int idx = blockIdx.x * 256 + threadIdx.x;
  if (idx >= N_IMG * 64 * 256) return;
  int p = idx & 255;
  int c0 = ((idx >> 8) & 63) << 2;
  int n = idx >> 14;
  const float* gn = g + (n * 256 + c0) * 128;
  const float* qn = quantT + (n * LEV) * 256 + p;
  float a0 = 0, a1 = 0, a2 = 0, a3 = 0;
  for (int lv = 0; lv < 128; lv++){
    float qv = qn[lv * 256];
    a0 += gn[lv] * qv; a1 += gn[128 + lv] * qv; a2 += gn[256 + lv] * qv; a3 += gn[384 + lv] * qv;
  }
  float* dst = outs + (n * 256 + c0) * 256 + p;
  dst[0] = a0; dst[256] = a1; dst[512] = a2; dst[768] = a3;
}

__global__ void resize_kernel(const float* __restrict__ outs, float* __restrict__ dout){
  int idx = blockIdx.x * 256 + threadIdx.x;
  if (idx >= N_IMG * 256 * P2304) return;
  int ow = idx % 48;
  int tmp = idx / 48;
  int oh = tmp % 48;
  int nc = tmp / 48;
  const float* src = outs + nc * 256;
  float fy = oh * (15.0f / 47.0f);
  float fx = ow * (15.0f / 47.0f);
  int y0 = (int)fy;
  int x0 = (int)fx;
  int y1 = min(y0 + 1, 15);
  int x1 = min(x0 + 1, 15);
  float wy = fy - (float)y0;
  float wx = fx - (float)x0;
  float v00 = src[y0 * 16 + x0], v01 = src[y0 * 16 + x1];
  float v10 = src[y1 * 16 + x0], v11 = src[y1 * 16 + x1];
  dout[idx] = v00 * (1.f - wy) * (1.f - wx) + v01 * (1.f - wy) * wx
            + v10 * wy * (1.f - wx) + v11 * wy * wx;
}

// ---------------- launcher ----------------
extern "C" void kernel_launch(void* const* d_in, const int* in_sizes, int n_in,
                              void* d_out, int out_size, void* d_ws, size_t ws_size,
                              hipStream_t stream)
{
  const float* x       = (const float*)d_in[0];
  const float* conv1_w = (const float*)d_in[1];
  const float* bn1_g   = (const float*)d_in[2];
  const float* bn1_b   = (const float*)d_in[3];
  const float* bn1_m   = (const float*)d_in[4];
  const float* bn1_v   = (const float*)d_in[5];
  const float* conv2_w = (const float*)d_in[6];
  const float* f1_w    = (const float*)d_in[7];
  const float* f2_w    = (const float*)d_in[8];
  const float* f2_g    = (const float*)d_in[9];
  const float* f2_b    = (const float*)d_in[10];
  const float* f2_m    = (const float*)d_in[11];
  const float* f2_v    = (const float*)d_in[12];
  const float* out1_w  = (const float*)d_in[13];
  const float* out1_g  = (const float*)d_in[14];
  const float* out1_b  = (const float*)d_in[15];
  const float* out1_m  = (const float*)d_in[16];
  const float* out1_v  = (const float*)d_in[17];
  const float* k_w     = (const float*)d_in[18];
  const float* q_w     = (const float*)d_in[19];
  const float* v_w     = (const float*)d_in[20];
  const float* out_w   = (const float*)d_in[21];
  const float* out_g   = (const float*)d_in[22];
  const float* out_b   = (const float*)d_in[23];
  const float* out_m   = (const float*)d_in[24];
  const float* out_v   = (const float*)d_in[25];

  float* ws = (float*)d_ws;
  float* dout = (float*)d_out;

  // fixed region (same layout as baseline)
  float* w_y   = ws;                  // 18874368 f (fast path: yh/yl u16 pair)
  float* w_x2  = ws + 18874368;       // 9437184 f
  float* w_W1h = ws + 28311552;       // 589824
  float* w_W1l = ws + 28901376;       // 589824
  float* w_W2h = ws + 29491200;       // 16384
  float* w_W2l = ws + 29507584;       // 16384
  float* w_s1  = ws + 29523968;       // 256
  float* w_t1  = ws + 29524224;       // 256  => fixed total 29524480 f
  // small buffers reuse the y region (only written after conv2 consumed y)
  float* w_xave = w_y + 0;
  float* w_xan  = w_y + 4096;
  float* w_cos  = w_y + 8192;
  float* w_qlv  = w_y + 90112;
  float* w_sta  = w_y + 94208;
  float* w_quant= w_y + 98304;
  float* w_h2   = w_y + 1409024;
  float* w_k    = w_y + 2981888;
  float* w_q    = w_y + 4030464;
  float* w_v    = w_y + 5079040;
  float* w_scT  = w_y + 6651904;
  float* w_f    = w_y + 7176192;
  float* w_g    = w_y + 8224768;
  float* w_outs = w_y + 9273344;
  float* w_s2   = w_y + 11370496;

  prep_w1_kernel<<<256, 256, 0, stream>>>(conv1_w, (uint4*)w_W1h, (uint4*)w_W1l);
  prep_w2_kernel<<<16, 256, 0, stream>>>(conv2_w, (uint4*)w_W2h, (uint4*)w_W2l);
  prep_bn_kernel<<<1, 256, 0, stream>>>(bn1_g, bn1_b, bn1_m, bn1_v, w_s1, w_t1);

  // --- conv1/conv2: fast path selection by available workspace ---
  const size_t BASE_F = 29524480;
  const size_t XPI_F  = 640000;                   // floats per image per array
  const size_t ws_f = ws_size / 4;
  int NCc = 0;
  if (ws_f >= BASE_F + 2 * 32 * XPI_F)      NCc = 32;
  else if (ws_f >= BASE_F + 2 * 16 * XPI_F) NCc = 16;

  if (NCc > 0){
    u16* w_xh = (u16*)(ws + BASE_F);
    u16* w_xl = w_xh + (size_t)NCc * 1280000;
    u16* w_yh = (u16*)w_y;                        // 18.87M u16 = 9437184 f
    u16* w_yl = (u16*)(w_y + 9437184);            // fills w_y region exactly
    const int nchunk = N_IMG / NCc;
    for (int c = 0; c < nchunk; ++c){
      int n0 = c * NCc;
      prep_x_kernel<<<NCc * 50, 256, 0, stream>>>(x, w_xh, w_xl, n0);
      if (NCc == 32)
        conv1_lds_kernel<32><<<1152, 256, 0, stream>>>(
            w_xh, w_xl, (const uint4*)w_W1h, (const uint4*)w_W1l, w_s1, w_t1,
            w_yh, w_yl, n0);
      else
        conv1_lds_kernel<16><<<576, 256, 0, stream>>>(
            w_xh, w_xl, (const uint4*)w_W1h, (const uint4*)w_W1l, w_s1, w_t1,
            w_yh, w_yl, n0);
    }
    conv2_lds_kernel<<<576, 256, 0, stream>>>(
        w_yh, w_yl, (const uint4*)w_W2h, (const uint4*)w_W2l, w_x2);
  } else {
    conv_mfma_kernel<9, 512, 2, true><<<1152, 256, 0, stream>>>(
        x, (const uint4*)w_W1h, (const uint4*)w_W1l, w_s1, w_t1, w_y);
    conv_mfma_kernel<1, 256, 1, false><<<576, 256, 0, stream>>>(
        w_y, (const uint4*)w_W2h, (const uint4*)w_W2l, w_s1, w_t1, w_x2);
  }

  xave_kernel<<<4096, 256, 0, stream>>>(w_x2, w_xave);
  xan_kernel<<<32, 128, 0, stream>>>(w_xave, w_xan);
  cos_kernel<<<288, 256, 0, stream>>>(w_x2, w_xan, w_cos);
  lbp_quant_sta_kernel<<<32, 256, 0, stream>>>(w_cos, w_qlv, w_quant, w_sta);
  h2_fused_kernel<<<512, 256, 0, stream>>>(f1_w, f2_w, w_qlv, w_sta,
                                           f2_g, f2_b, f2_m, f2_v, w_h2);
  out1_fused_kernel<<<1024, 256, 0, stream>>>(out1_w, w_h2, w_xave,
                                              out1_g, out1_b, out1_m, out1_v, w_s2);
  gemm_kqv_kernel<<<3072, 256, 0, stream>>>(k_w, q_w, v_w, w_s2, w_k, w_q, w_v);
  attn_scsm_kernel<<<512, 256, 0, stream>>>(w_k, w_q, w_scT);
  attn_f_kernel<<<1024, 256, 0, stream>>>(w_v, w_scT, w_f);
  gemm_w_kernel<<<1024, 256, 0, stream>>>(out_w, w_f, w_g, 256, 256, N_IMG * 64 * 128, 1,
                                          out_g, out_b, out_m, out_v);
  final_kernel<<<2048, 256, 0, stream>>>(w_g, w_quant, w_outs);
  resize_kernel<<<73728, 256, 0, stream>>>(w_outs, dout);
}